// Round 2
// baseline (662.235 us; speedup 1.0000x reference)
//
#include <hip/hip_runtime.h>

typedef unsigned short u16;
typedef __bf16 bf16x8 __attribute__((ext_vector_type(8)));
typedef float f32x4 __attribute__((ext_vector_type(4)));

// Problem constants
#define SEQ   4096
#define DM    1024
#define DI    2048
#define NTOK  8192      // BATCH * SEQ
#define NXP   68        // DT_RANK + 2*D_STATE
#define DTR   64        // DT_RANK
#define NCH   4096      // BATCH * DI channels for scan
#define CHUNK 64
#define NCHK  64        // SEQ / CHUNK

__device__ __forceinline__ float bf2f(u16 v) {
  union { unsigned u; float f; } x; x.u = ((unsigned)v) << 16; return x.f;
}
__device__ __forceinline__ u16 f2bf(float f) {
  unsigned u = __float_as_uint(f);
  return (u16)((u + 0x7FFFu + ((u >> 16) & 1u)) >> 16);   // RNE
}

// ---------------------------------------------------------------------------
// Input dtype detection: if inputs are f32, the LOW u16 of each f32 word is
// random mantissa bits -> decoded-as-bf16 exponent is uniform; huge exponents
// (e > 167, i.e. |v| > 2^40) occur ~34%/element. Genuine bf16 N(0,1) data
// never exceeds e=130. flag=1 -> inputs (and output) are f32.
// ---------------------------------------------------------------------------
__global__ __launch_bounds__(256)
void detect_kernel(const u16* __restrict__ x, int* __restrict__ flag)
{
  __shared__ int tot;
  if (threadIdx.x == 0) tot = 0;
  __syncthreads();
  int cnt = 0;
  for (int i = threadIdx.x; i < 4096; i += 256) {
    const int e = (x[2 * i] >> 7) & 0xFF;
    if (e > 167) cnt++;
  }
  atomicAdd(&tot, cnt);
  __syncthreads();
  if (threadIdx.x == 0) flag[0] = (tot >= 8) ? 1 : 0;
}

// Generic dtype-normalizing copy: src (f32 or bf16 per flag) -> bf16 dst
__global__ __launch_bounds__(256)
void convert_kernel(const void* __restrict__ src, u16* __restrict__ dst, int n,
                    const int* __restrict__ flag)
{
  const int i = blockIdx.x * 256 + threadIdx.x;
  if (i < n)
    dst[i] = (*flag) ? f2bf(((const float*)src)[i]) : ((const u16*)src)[i];
}

// All 11 small vectors in one launch (24576 elements total)
__global__ __launch_bounds__(256)
void convert_small_kernel(const void* s0, const void* s1, const void* s2,
                          const void* s3, const void* s4, const void* s5,
                          const void* s6, const void* s7, const void* s8,
                          const void* s9, const void* s10,
                          u16* __restrict__ dst, const int* __restrict__ flag)
{
  const int i = blockIdx.x * 256 + threadIdx.x;
  if (i >= 24576) return;
  const void* src; int off;
  if      (i < 8192)  { src = s0;  off = i; }          // conv_w  [2048*4]
  else if (i < 10240) { src = s1;  off = i - 8192; }   // conv_b  [2048]
  else if (i < 12288) { src = s2;  off = i - 10240; }  // b_dt    [2048]
  else if (i < 16384) { src = s3;  off = i - 12288; }  // a_log   [2048*2]
  else if (i < 18432) { src = s4;  off = i - 16384; }  // d_skip  [2048]
  else if (i < 19456) { src = s5;  off = i - 18432; }  // ln1_g   [1024]
  else if (i < 20480) { src = s6;  off = i - 19456; }  // ln1_b
  else if (i < 21504) { src = s7;  off = i - 20480; }  // ln2_g
  else if (i < 22528) { src = s8;  off = i - 21504; }  // ln2_b
  else if (i < 23552) { src = s9;  off = i - 22528; }  // ffn_b1
  else                { src = s10; off = i - 23552; }  // ffn_b2
  dst[i] = (*flag) ? f2bf(((const float*)src)[off]) : ((const u16*)src)[off];
}

// ---------------------------------------------------------------------------
// LayerNorm over rows of 1024; output bf16.
// DUAL=true: input dtype per runtime flag (f32 if *flag). DUAL=false: f32.
// ---------------------------------------------------------------------------
template<bool DUAL>
__global__ __launch_bounds__(256)
void ln_kernel(const void* __restrict__ xin, const u16* __restrict__ gw,
               const u16* __restrict__ bw, u16* __restrict__ outp,
               const int* __restrict__ flag)
{
  const int row = blockIdx.x;
  const int tid = threadIdx.x;
  const bool isf32 = DUAL ? (*flag != 0) : true;
  const float* xf = (const float*)xin;
  const u16*   xb = (const u16*)xin;
  float v[4];
#pragma unroll
  for (int k = 0; k < 4; ++k) {
    size_t idx = (size_t)row * DM + tid + k * 256;
    v[k] = isf32 ? xf[idx] : bf2f(xb[idx]);
  }
  float s = v[0] + v[1] + v[2] + v[3];
  float s2 = v[0]*v[0] + v[1]*v[1] + v[2]*v[2] + v[3]*v[3];
#pragma unroll
  for (int off = 32; off > 0; off >>= 1) {
    s  += __shfl_down(s,  off);
    s2 += __shfl_down(s2, off);
  }
  __shared__ float red[8];
  const int wv = tid >> 6, lane = tid & 63;
  if (lane == 0) { red[wv] = s; red[4 + wv] = s2; }
  __syncthreads();
  if (tid == 0) {
    float ts = red[0] + red[1] + red[2] + red[3];
    float t2 = red[4] + red[5] + red[6] + red[7];
    float mu = ts * (1.f / DM);
    float var = t2 * (1.f / DM) - mu * mu;
    red[0] = mu; red[1] = rsqrtf(var + 1e-5f);
  }
  __syncthreads();
  const float mu = red[0], rs = red[1];
#pragma unroll
  for (int k = 0; k < 4; ++k) {
    int col = tid + k * 256;
    size_t idx = (size_t)row * DM + col;
    outp[idx] = f2bf((v[k] - mu) * rs * bf2f(gw[col]) + bf2f(bw[col]));
  }
}

// ---------------------------------------------------------------------------
// bf16 GEMM: C[M,N] = A[M,K] @ B[N,K]^T  (torch Linear weight layout).
// 128x128 block tile, BK=32, 4 waves each 64x64 (4x4 of 16x16x32 MFMA).
// Requires M % 128 == 0, K % 32 == 0; N arbitrary (guarded).
// EPI: 0 f32 store | 1 bf16 store | 2 +bias,softplus->bf16 |
//      3 +x (dtype per flag) -> f32 | 4 +bias,relu->bf16 |
//      5 +bias+addf32 -> out (bf16 or f32 per flag)
// ---------------------------------------------------------------------------
template<int EPI>
__global__ __launch_bounds__(256, 2)
void gemm_kernel(const u16* __restrict__ A, const u16* __restrict__ B,
                 int M, int N, int K,
                 const u16* __restrict__ bias, const u16* __restrict__ addbf,
                 const float* __restrict__ addf, const int* __restrict__ dtflag,
                 void* __restrict__ Cp)
{
  __shared__ __align__(16) u16 sA[128 * 32];
  __shared__ __align__(16) u16 sB[128 * 32];
  const int tid = threadIdx.x;
  const int m0 = blockIdx.y * 128;
  const int n0 = blockIdx.x * 128;
  const int lane = tid & 63;
  const int wv = tid >> 6;
  const int wm = (wv & 1) * 64;
  const int wn = (wv >> 1) * 64;
  const int r = lane & 15;       // A row / B col within 16-tile
  const int q = lane >> 4;       // k-quad

  const int row_l = tid >> 2;            // 0..63 staging row
  const int kk_l  = (tid & 3) * 8;       // 0,8,16,24

  const int fl = (EPI == 3 || EPI == 5) ? *dtflag : 0;

  f32x4 acc[4][4];
#pragma unroll
  for (int i = 0; i < 4; ++i)
#pragma unroll
    for (int j = 0; j < 4; ++j)
#pragma unroll
      for (int t = 0; t < 4; ++t) acc[i][j][t] = 0.f;

  const int nk = K >> 5;
  for (int kt = 0; kt < nk; ++kt) {
    const int k0 = kt << 5;
    const u16* Ag = A + (size_t)(m0 + row_l) * K + k0 + kk_l;
    uint4 va0 = *reinterpret_cast<const uint4*>(Ag);
    uint4 va1 = *reinterpret_cast<const uint4*>(Ag + (size_t)64 * K);
    uint4 vb0 = {0u, 0u, 0u, 0u}, vb1 = {0u, 0u, 0u, 0u};
    const u16* Bg = B + (size_t)(n0 + row_l) * K + k0 + kk_l;
    if (n0 + row_l < N)      vb0 = *reinterpret_cast<const uint4*>(Bg);
    if (n0 + row_l + 64 < N) vb1 = *reinterpret_cast<const uint4*>(Bg + (size_t)64 * K);
    __syncthreads();   // all waves done reading LDS from previous iter
    *reinterpret_cast<uint4*>(&sA[row_l * 32 + kk_l])        = va0;
    *reinterpret_cast<uint4*>(&sA[(row_l + 64) * 32 + kk_l]) = va1;
    *reinterpret_cast<uint4*>(&sB[row_l * 32 + kk_l])        = vb0;
    *reinterpret_cast<uint4*>(&sB[(row_l + 64) * 32 + kk_l]) = vb1;
    __syncthreads();
    bf16x8 af[4], bfr[4];
#pragma unroll
    for (int i = 0; i < 4; ++i)
      af[i] = *reinterpret_cast<const bf16x8*>(&sA[(wm + i * 16 + r) * 32 + q * 8]);
#pragma unroll
    for (int j = 0; j < 4; ++j)
      bfr[j] = *reinterpret_cast<const bf16x8*>(&sB[(wn + j * 16 + r) * 32 + q * 8]);
#pragma unroll
    for (int i = 0; i < 4; ++i)
#pragma unroll
      for (int j = 0; j < 4; ++j)
        acc[i][j] = __builtin_amdgcn_mfma_f32_16x16x32_bf16(af[i], bfr[j], acc[i][j], 0, 0, 0);
  }

  // epilogue: D row = wm+i*16+q*4+t (M dim), col = wn+j*16+r (N dim)
#pragma unroll
  for (int i = 0; i < 4; ++i) {
#pragma unroll
    for (int j = 0; j < 4; ++j) {
#pragma unroll
      for (int t = 0; t < 4; ++t) {
        const int row = m0 + wm + i * 16 + q * 4 + t;
        const int col = n0 + wn + j * 16 + r;
        if (col < N) {
          const size_t idx = (size_t)row * N + col;
          float v = acc[i][j][t];
          if (EPI == 0) {
            ((float*)Cp)[idx] = v;
          } else if (EPI == 1) {
            ((u16*)Cp)[idx] = f2bf(v);
          } else if (EPI == 2) {           // dt = softplus(v + b_dt)
            v += bf2f(bias[col]);
            v = (v > 20.f) ? v : log1pf(expf(v));
            ((u16*)Cp)[idx] = f2bf(v);
          } else if (EPI == 3) {           // h = x + mamba_out (f32 out)
            v += fl ? addf[idx] : bf2f(addbf[idx]);
            ((float*)Cp)[idx] = v;
          } else if (EPI == 4) {           // relu(v + b1) -> bf16
            v += bf2f(bias[col]);
            ((u16*)Cp)[idx] = f2bf(fmaxf(v, 0.f));
          } else {                         // out = h + v + b2, dtype per flag
            v += bf2f(bias[col]) + addf[idx];
            if (fl) ((float*)Cp)[idx] = v;
            else    ((u16*)Cp)[idx] = f2bf(v);
          }
        }
      }
    }
  }
}

// ---------------------------------------------------------------------------
// Depthwise causal conv (k=4) + bias + SiLU. xp: [NTOK, DI] bf16 -> u.
// ---------------------------------------------------------------------------
__global__ __launch_bounds__(256)
void conv_silu_kernel(const u16* __restrict__ xp, const u16* __restrict__ cw,
                      const u16* __restrict__ cb, u16* __restrict__ u)
{
  const int i = blockIdx.x * 256 + threadIdx.x;   // NTOK*DI
  const int d = i & (DI - 1);
  const int token = i >> 11;
  const int t = token & (SEQ - 1);
  float acc = bf2f(cb[d]);
#pragma unroll
  for (int j = 0; j < 4; ++j) {
    const int tt = t - 3 + j;
    if (tt >= 0)
      acc += bf2f(cw[d * 4 + j]) * bf2f(xp[(size_t)(token - 3 + j) * DI + d]);
  }
  const float sg = 1.f / (1.f + expf(-acc));
  u[i] = f2bf(acc * sg);
}

// x_dbl[:, :64] -> bf16 dt_raw for the dt GEMM
__global__ __launch_bounds__(256)
void extract_dt_kernel(const float* __restrict__ xdbl, u16* __restrict__ dtraw)
{
  const int i = blockIdx.x * 256 + threadIdx.x;   // NTOK*64
  const int row = i >> 6, c = i & 63;
  dtraw[i] = f2bf(xdbl[(size_t)row * NXP + c]);
}

// ---------------------------------------------------------------------------
// Chunked SSM scan (N=2): pass1 zero-init per-chunk scan; pass2 sequential
// chunk combine (chunk A-product = exp(A*sum(dt))); pass3 re-scan + fused
// y_final = (y + d_skip*u) * silu(z). yb may alias dtb (in-place safe).
// ---------------------------------------------------------------------------
__global__ __launch_bounds__(256)
void scan_pass1(const u16* __restrict__ dtb, const u16* __restrict__ ub,
                const float* __restrict__ xdbl, const u16* __restrict__ a_log,
                float* __restrict__ S, float* __restrict__ hf0, float* __restrict__ hf1)
{
  const int g = blockIdx.x * 256 + threadIdx.x;   // NCHK*NCH
  const int ch = g & (NCH - 1);
  const int c = g >> 12;
  const int b = ch >> 11;
  const int d = ch & (DI - 1);
  const float A0 = -expf(bf2f(a_log[d * 2 + 0]));
  const float A1 = -expf(bf2f(a_log[d * 2 + 1]));
  float h0 = 0.f, h1 = 0.f, s = 0.f;
  const int row0 = b * SEQ + c * CHUNK;
  for (int i = 0; i < CHUNK; ++i) {
    const size_t row = row0 + i;
    const float dt = bf2f(dtb[row * DI + d]);
    const float uu = bf2f(ub[row * DI + d]);
    const float B0 = xdbl[row * NXP + 64];
    const float B1 = xdbl[row * NXP + 65];
    const float dtu = dt * uu;
    h0 = expf(A0 * dt) * h0 + dtu * B0;
    h1 = expf(A1 * dt) * h1 + dtu * B1;
    s += dt;
  }
  S[g] = s; hf0[g] = h0; hf1[g] = h1;
}

__global__ __launch_bounds__(256)
void scan_pass2(const float* __restrict__ S, const float* __restrict__ hf0,
                const float* __restrict__ hf1, const u16* __restrict__ a_log,
                float* __restrict__ hi0, float* __restrict__ hi1)
{
  const int ch = blockIdx.x * 256 + threadIdx.x;  // NCH
  const int d = ch & (DI - 1);
  const float A0 = -expf(bf2f(a_log[d * 2 + 0]));
  const float A1 = -expf(bf2f(a_log[d * 2 + 1]));
  float h0 = 0.f, h1 = 0.f;
  for (int c = 0; c < NCHK; ++c) {
    const int g = c * NCH + ch;
    hi0[g] = h0; hi1[g] = h1;
    const float s = S[g];
    h0 = expf(A0 * s) * h0 + hf0[g];
    h1 = expf(A1 * s) * h1 + hf1[g];
  }
}

__global__ __launch_bounds__(256)
void scan_pass3(const u16* __restrict__ dtb, const u16* __restrict__ ub,
                const float* __restrict__ xdbl, const u16* __restrict__ zbuf,
                const u16* __restrict__ a_log, const u16* __restrict__ d_skip,
                const float* __restrict__ hi0, const float* __restrict__ hi1,
                u16* __restrict__ yb)
{
  const int g = blockIdx.x * 256 + threadIdx.x;
  const int ch = g & (NCH - 1);
  const int c = g >> 12;
  const int b = ch >> 11;
  const int d = ch & (DI - 1);
  const float A0 = -expf(bf2f(a_log[d * 2 + 0]));
  const float A1 = -expf(bf2f(a_log[d * 2 + 1]));
  const float dsk = bf2f(d_skip[d]);
  float h0 = hi0[g], h1 = hi1[g];
  const int row0 = b * SEQ + c * CHUNK;
  for (int i = 0; i < CHUNK; ++i) {
    const size_t row = row0 + i;
    const float dt = bf2f(dtb[row * DI + d]);
    const float uu = bf2f(ub[row * DI + d]);
    const float B0 = xdbl[row * NXP + 64];
    const float B1 = xdbl[row * NXP + 65];
    const float C0 = xdbl[row * NXP + 66];
    const float C1 = xdbl[row * NXP + 67];
    const float dtu = dt * uu;
    h0 = expf(A0 * dt) * h0 + dtu * B0;
    h1 = expf(A1 * dt) * h1 + dtu * B1;
    const float y = h0 * C0 + h1 * C1;
    const float z = bf2f(zbuf[row * DI + d]);
    const float sz = z / (1.f + expf(-z));
    yb[row * DI + d] = f2bf((y + dsk * uu) * sz);   // in-place over dtb: ok
  }
}

// ---------------------------------------------------------------------------
extern "C" void kernel_launch(void* const* d_in, const int* in_sizes, int n_in,
                              void* d_out, int out_size, void* d_ws, size_t ws_size,
                              hipStream_t stream)
{
  const void* x       = d_in[0];
  const void* w_in    = d_in[1];
  const void* conv_w  = d_in[2];
  const void* conv_b  = d_in[3];
  const void* w_xproj = d_in[4];
  const void* w_dt    = d_in[5];
  const void* b_dt    = d_in[6];
  const void* a_log   = d_in[7];
  const void* d_skip  = d_in[8];
  const void* w_out   = d_in[9];
  const void* ln1_g   = d_in[10];
  const void* ln1_b   = d_in[11];
  const void* ln2_g   = d_in[12];
  const void* ln2_b   = d_in[13];
  const void* ffn_w1  = d_in[14];
  const void* ffn_b1  = d_in[15];
  const void* ffn_w2  = d_in[16];
  const void* ffn_b2  = d_in[17];
  char* ws = (char*)d_ws;

  // ---- workspace layout (total ~128.1 MB), aggressive overlay ----
  const size_t o_flag  = 0;
  const size_t o_small = 256;                                   // 24576 bf16
  const size_t o_cwout = o_small + 65536;                       // 65,792
  const size_t o_cff1  = o_cwout + (size_t)DM * DI * 2;         // +4,194,304
  const size_t o_cff2  = o_cff1  + (size_t)DM * DM * 2;         // +2,097,152
  const size_t o_cxp   = o_cff2  + (size_t)DM * DM * 2;         // +2,097,152
  const size_t o_cwdt  = o_cxp   + (size_t)NXP * DI * 2;        // +278,528
  const size_t o_xn    = 9437184;                               // 9 MiB (> 8,995,072)
  const size_t o_xp    = o_xn   + (size_t)NTOK * DM * 2;        // +16 MiB
  const size_t o_z     = o_xp   + (size_t)NTOK * DI * 2;        // +32 MiB
  const size_t o_u     = o_z    + (size_t)NTOK * DI * 2;        // +32 MiB
  const size_t o_xdbl  = o_u    + (size_t)NTOK * DI * 2;        // +32 MiB
  const size_t o_S     = o_xdbl + (size_t)NTOK * NXP * 4;       // +2,228,224
  const size_t o_hf0   = o_S    + (size_t)NCHK * NCH * 4;
  const size_t o_hf1   = o_hf0  + (size_t)NCHK * NCH * 4;
  const size_t o_hi0   = o_hf1  + (size_t)NCHK * NCH * 4;
  const size_t o_hi1   = o_hi0  + (size_t)NCHK * NCH * 4;

  int*   flagp   = (int*)(ws + o_flag);
  u16*   csmall  = (u16*)(ws + o_small);
  u16*   c_convw = csmall +     0;
  u16*   c_convb = csmall +  8192;
  u16*   c_bdt   = csmall + 10240;
  u16*   c_alog  = csmall + 12288;
  u16*   c_dskip = csmall + 16384;
  u16*   c_ln1g  = csmall + 18432;
  u16*   c_ln1b  = csmall + 19456;
  u16*   c_ln2g  = csmall + 20480;
  u16*   c_ln2b  = csmall + 21504;
  u16*   c_fb1   = csmall + 22528;
  u16*   c_fb2   = csmall + 23552;
  u16*   c_wout  = (u16*)(ws + o_cwout);
  u16*   c_ff1   = (u16*)(ws + o_cff1);
  u16*   c_ff2   = (u16*)(ws + o_cff2);
  u16*   c_xproj = (u16*)(ws + o_cxp);
  u16*   c_wdt   = (u16*)(ws + o_cwdt);
  u16*   c_win   = (u16*)(ws + o_u);     // overlays u: dead before conv writes u
  u16*   xn      = (u16*)(ws + o_xn);
  u16*   xp      = (u16*)(ws + o_xp);    // -> dtb -> yb (in-place reuse)
  u16*   zb      = (u16*)(ws + o_z);     // -> h (f32) after pass3
  u16*   u       = (u16*)(ws + o_u);     // -> f1 after pass3
  float* xdbl    = (float*)(ws + o_xdbl);
  u16*   dtraw   = (u16*)(ws + o_xn);    // overlays xn (dead after in_proj)
  u16*   dtb     = xp;
  u16*   yb      = xp;
  float* S       = (float*)(ws + o_S);
  float* hf0     = (float*)(ws + o_hf0);
  float* hf1     = (float*)(ws + o_hf1);
  float* hi0     = (float*)(ws + o_hi0);
  float* hi1     = (float*)(ws + o_hi1);
  float* h       = (float*)(ws + o_z);   // overlays z (dead after pass3)
  u16*   hn      = (u16*)(ws + o_xn);    // overlays xn/dtraw (dead)
  u16*   f1      = (u16*)(ws + o_u);     // overlays u (dead)

  const dim3 blk(256);

  // 0) detect input dtype, normalize all params to canonical bf16
  detect_kernel<<<1, blk, 0, stream>>>((const u16*)x, flagp);
  convert_kernel<<<(2 * DI * DM) / 256, blk, 0, stream>>>(w_in, c_win, 2 * DI * DM, flagp);
  convert_kernel<<<(NXP * DI + 255) / 256, blk, 0, stream>>>(w_xproj, c_xproj, NXP * DI, flagp);
  convert_kernel<<<(DI * DTR) / 256, blk, 0, stream>>>(w_dt, c_wdt, DI * DTR, flagp);
  convert_kernel<<<(DM * DI) / 256, blk, 0, stream>>>(w_out, c_wout, DM * DI, flagp);
  convert_kernel<<<(DM * DM) / 256, blk, 0, stream>>>(ffn_w1, c_ff1, DM * DM, flagp);
  convert_kernel<<<(DM * DM) / 256, blk, 0, stream>>>(ffn_w2, c_ff2, DM * DM, flagp);
  convert_small_kernel<<<96, blk, 0, stream>>>(conv_w, conv_b, b_dt, a_log, d_skip,
                                               ln1_g, ln1_b, ln2_g, ln2_b, ffn_b1, ffn_b2,
                                               csmall, flagp);

  // 1) LN1(x) -> xn (bf16)
  ln_kernel<true><<<NTOK, blk, 0, stream>>>(x, c_ln1g, c_ln1b, xn, flagp);
  // 2) xp = xn @ w_in[:2048]^T ; z = xn @ w_in[2048:]^T
  gemm_kernel<1><<<dim3(16, 64), blk, 0, stream>>>(xn, c_win, NTOK, DI, DM,
                                                   nullptr, nullptr, nullptr, flagp, xp);
  gemm_kernel<1><<<dim3(16, 64), blk, 0, stream>>>(xn, c_win + (size_t)DI * DM, NTOK, DI, DM,
                                                   nullptr, nullptr, nullptr, flagp, zb);
  // 3) u = silu(causal_conv(xp) + conv_b)   (overwrites c_win region: dead)
  conv_silu_kernel<<<NTOK * DI / 256, blk, 0, stream>>>(xp, c_convw, c_convb, u);
  // 4) x_dbl = u @ w_xproj^T  [8192,68] f32
  gemm_kernel<0><<<dim3(1, 64), blk, 0, stream>>>(u, c_xproj, NTOK, NXP, DI,
                                                  nullptr, nullptr, nullptr, flagp, xdbl);
  // 5) dt_raw = bf16(x_dbl[:, :64])
  extract_dt_kernel<<<NTOK * DTR / 256, blk, 0, stream>>>(xdbl, dtraw);
  // 6) dt = softplus(dt_raw @ w_dt^T + b_dt) -> dtb (reuses xp: dead)
  gemm_kernel<2><<<dim3(16, 64), blk, 0, stream>>>(dtraw, c_wdt, NTOK, DI, DTR,
                                                   c_bdt, nullptr, nullptr, flagp, dtb);
  // 7-9) chunked scan -> yb = (y + d_skip*u) * silu(z)  (in-place over dtb)
  scan_pass1<<<NCHK * NCH / 256, blk, 0, stream>>>(dtb, u, xdbl, c_alog, S, hf0, hf1);
  scan_pass2<<<NCH / 256, blk, 0, stream>>>(S, hf0, hf1, c_alog, hi0, hi1);
  scan_pass3<<<NCHK * NCH / 256, blk, 0, stream>>>(dtb, u, xdbl, zb, c_alog, c_dskip,
                                                   hi0, hi1, yb);
  // 10) h = x + yb @ w_out^T  (f32, overlays z: dead)
  gemm_kernel<3><<<dim3(8, 64), blk, 0, stream>>>(yb, c_wout, NTOK, DM, DI,
                                                  nullptr, (const u16*)x, (const float*)x,
                                                  flagp, h);
  // 11) LN2(h) -> hn (overlays xn: dead)
  ln_kernel<false><<<NTOK, blk, 0, stream>>>(h, c_ln2g, c_ln2b, hn, flagp);
  // 12) f1 = relu(hn @ ffn_w1^T + b1) (overlays u: dead)
  gemm_kernel<4><<<dim3(8, 64), blk, 0, stream>>>(hn, c_ff1, NTOK, DM, DM,
                                                  c_fb1, nullptr, nullptr, flagp, f1);
  // 13) out = h + f1 @ ffn_w2^T + b2  (bf16 or f32 per flag)
  gemm_kernel<5><<<dim3(8, 64), blk, 0, stream>>>(f1, c_ff2, NTOK, DM, DM,
                                                  c_fb2, nullptr, h, flagp, d_out);
}

// Round 3
// 524.405 us; speedup vs baseline: 1.2628x; 1.2628x over previous
//
#include <hip/hip_runtime.h>

typedef unsigned short u16;
typedef __bf16 bf16x8 __attribute__((ext_vector_type(8)));
typedef float f32x4 __attribute__((ext_vector_type(4)));

// Problem constants
#define SEQ   4096
#define DM    1024
#define DI    2048
#define NTOK  8192      // BATCH * SEQ
#define NXP   68        // DT_RANK + 2*D_STATE
#define DTR   64        // DT_RANK
#define NCH   4096      // BATCH * DI channels for scan
#define CHUNK 64
#define NCHK  64        // SEQ / CHUNK

__device__ __forceinline__ float bf2f(u16 v) {
  union { unsigned u; float f; } x; x.u = ((unsigned)v) << 16; return x.f;
}
__device__ __forceinline__ u16 f2bf(float f) {
  unsigned u = __float_as_uint(f);
  return (u16)((u + 0x7FFFu + ((u >> 16) & 1u)) >> 16);   // RNE
}

// async global->LDS DMA, 16B/lane; LDS dest = wave-uniform base + lane*16
__device__ __forceinline__ void g2l16(const u16* g, u16* l) {
  __builtin_amdgcn_global_load_lds(
      (const __attribute__((address_space(1))) unsigned int*)g,
      (__attribute__((address_space(3))) unsigned int*)l, 16, 0, 0);
}

// ---------------------------------------------------------------------------
// Input dtype detection (f32 inputs -> low u16 has huge bf16 exponents)
// ---------------------------------------------------------------------------
__global__ __launch_bounds__(256)
void detect_kernel(const u16* __restrict__ x, int* __restrict__ flag)
{
  __shared__ int tot;
  if (threadIdx.x == 0) tot = 0;
  __syncthreads();
  int cnt = 0;
  for (int i = threadIdx.x; i < 4096; i += 256) {
    const int e = (x[2 * i] >> 7) & 0xFF;
    if (e > 167) cnt++;
  }
  atomicAdd(&tot, cnt);
  __syncthreads();
  if (threadIdx.x == 0) flag[0] = (tot >= 8) ? 1 : 0;
}

__global__ __launch_bounds__(256)
void convert_kernel(const void* __restrict__ src, u16* __restrict__ dst, int n,
                    const int* __restrict__ flag)
{
  const int i = blockIdx.x * 256 + threadIdx.x;
  if (i < n)
    dst[i] = (*flag) ? f2bf(((const float*)src)[i]) : ((const u16*)src)[i];
}

__global__ __launch_bounds__(256)
void convert_small_kernel(const void* s0, const void* s1, const void* s2,
                          const void* s3, const void* s4, const void* s5,
                          const void* s6, const void* s7, const void* s8,
                          const void* s9, const void* s10,
                          u16* __restrict__ dst, const int* __restrict__ flag)
{
  const int i = blockIdx.x * 256 + threadIdx.x;
  if (i >= 24576) return;
  const void* src; int off;
  if      (i < 8192)  { src = s0;  off = i; }          // conv_w  [2048*4]
  else if (i < 10240) { src = s1;  off = i - 8192; }   // conv_b
  else if (i < 12288) { src = s2;  off = i - 10240; }  // b_dt
  else if (i < 16384) { src = s3;  off = i - 12288; }  // a_log
  else if (i < 18432) { src = s4;  off = i - 16384; }  // d_skip
  else if (i < 19456) { src = s5;  off = i - 18432; }  // ln1_g
  else if (i < 20480) { src = s6;  off = i - 19456; }  // ln1_b
  else if (i < 21504) { src = s7;  off = i - 20480; }  // ln2_g
  else if (i < 22528) { src = s8;  off = i - 21504; }  // ln2_b
  else if (i < 23552) { src = s9;  off = i - 22528; }  // ffn_b1
  else                { src = s10; off = i - 23552; }  // ffn_b2
  dst[i] = (*flag) ? f2bf(((const float*)src)[off]) : ((const u16*)src)[off];
}

// ---------------------------------------------------------------------------
// LayerNorm over rows of 1024 -> bf16
// ---------------------------------------------------------------------------
template<bool DUAL>
__global__ __launch_bounds__(256)
void ln_kernel(const void* __restrict__ xin, const u16* __restrict__ gw,
               const u16* __restrict__ bw, u16* __restrict__ outp,
               const int* __restrict__ flag)
{
  const int row = blockIdx.x;
  const int tid = threadIdx.x;
  const bool isf32 = DUAL ? (*flag != 0) : true;
  const float* xf = (const float*)xin;
  const u16*   xb = (const u16*)xin;
  float v[4];
#pragma unroll
  for (int k = 0; k < 4; ++k) {
    size_t idx = (size_t)row * DM + tid + k * 256;
    v[k] = isf32 ? xf[idx] : bf2f(xb[idx]);
  }
  float s = v[0] + v[1] + v[2] + v[3];
  float s2 = v[0]*v[0] + v[1]*v[1] + v[2]*v[2] + v[3]*v[3];
#pragma unroll
  for (int off = 32; off > 0; off >>= 1) {
    s  += __shfl_down(s,  off);
    s2 += __shfl_down(s2, off);
  }
  __shared__ float red[8];
  const int wv = tid >> 6, lane = tid & 63;
  if (lane == 0) { red[wv] = s; red[4 + wv] = s2; }
  __syncthreads();
  if (tid == 0) {
    float ts = red[0] + red[1] + red[2] + red[3];
    float t2 = red[4] + red[5] + red[6] + red[7];
    float mu = ts * (1.f / DM);
    float var = t2 * (1.f / DM) - mu * mu;
    red[0] = mu; red[1] = rsqrtf(var + 1e-5f);
  }
  __syncthreads();
  const float mu = red[0], rs = red[1];
#pragma unroll
  for (int k = 0; k < 4; ++k) {
    int col = tid + k * 256;
    size_t idx = (size_t)row * DM + col;
    outp[idx] = f2bf((v[k] - mu) * rs * bf2f(gw[col]) + bf2f(bw[col]));
  }
}

// ---------------------------------------------------------------------------
// bf16 MFMA GEMM: C[M,N] = A[M,K] @ B[N,K]^T.  128x128 tile, BK=32,
// global_load_lds(16B) staging, XCD swizzle (8 y-bands, sweep x in-band).
// Requires: M%128==0, N%128==0, K%32==0, gridDim.x == (N/128)*64, N/128==1<<LNBX.
// EPI: 1 bf16 | 2 +bias,softplus->bf16 | 3 +x(flag dtype)->f32 |
//      4 +bias,relu->bf16 | 5 +bias+addf32 -> out(bf16/f32 per flag)
// ---------------------------------------------------------------------------
template<int EPI, int LNBX>
__global__ __launch_bounds__(256, 2)
void gemm_kernel(const u16* __restrict__ A, const u16* __restrict__ B,
                 int M, int N, int K,
                 const u16* __restrict__ bias, const u16* __restrict__ addbf,
                 const float* __restrict__ addf, const int* __restrict__ dtflag,
                 void* __restrict__ Cp)
{
  __shared__ __align__(16) u16 sA[128 * 32];
  __shared__ __align__(16) u16 sB[128 * 32];
  const int tid = threadIdx.x;
  const int b = blockIdx.x;
  const int xcd = b & 7;
  const int kk = b >> 3;
  const int bx = kk & ((1 << LNBX) - 1);
  const int by = xcd * 8 + (kk >> LNBX);
  const int m0 = by * 128;
  const int n0 = bx * 128;
  const int lane = tid & 63;
  const int wv = tid >> 6;
  const int wm = (wv & 1) * 64;
  const int wn = (wv >> 1) * 64;
  const int r = lane & 15;
  const int q = lane >> 4;

  // staging: wave wv DMAs rows [32wv,32wv+32) of each tile as two 16-row chunks
  const int pr = lane >> 2;            // 0..15 row in chunk
  const int pk = (lane & 3) * 8;       // k elem offset 0,8,16,24
  u16* lA0 = &sA[(wv * 2 + 0) * 512];
  u16* lA1 = &sA[(wv * 2 + 1) * 512];
  u16* lB0 = &sB[(wv * 2 + 0) * 512];
  u16* lB1 = &sB[(wv * 2 + 1) * 512];
  const u16* gA0 = A + (size_t)(m0 + wv * 32 + pr) * K + pk;
  const u16* gA1 = gA0 + (size_t)16 * K;
  const u16* gB0 = B + (size_t)(n0 + wv * 32 + pr) * K + pk;
  const u16* gB1 = gB0 + (size_t)16 * K;

  const int fl = (EPI == 3 || EPI == 5) ? *dtflag : 0;

  f32x4 acc[4][4];
#pragma unroll
  for (int i = 0; i < 4; ++i)
#pragma unroll
    for (int j = 0; j < 4; ++j)
#pragma unroll
      for (int t = 0; t < 4; ++t) acc[i][j][t] = 0.f;

  const int nk = K >> 5;
  for (int kt = 0; kt < nk; ++kt) {
    g2l16(gA0, lA0); g2l16(gA1, lA1);
    g2l16(gB0, lB0); g2l16(gB1, lB1);
    gA0 += 32; gA1 += 32; gB0 += 32; gB1 += 32;
    __syncthreads();                 // drains vmcnt: staging complete
    bf16x8 af[4], bfr[4];
#pragma unroll
    for (int i = 0; i < 4; ++i)
      af[i] = *reinterpret_cast<const bf16x8*>(&sA[(wm + i * 16 + r) * 32 + q * 8]);
#pragma unroll
    for (int j = 0; j < 4; ++j)
      bfr[j] = *reinterpret_cast<const bf16x8*>(&sB[(wn + j * 16 + r) * 32 + q * 8]);
#pragma unroll
    for (int i = 0; i < 4; ++i)
#pragma unroll
      for (int j = 0; j < 4; ++j)
        acc[i][j] = __builtin_amdgcn_mfma_f32_16x16x32_bf16(af[i], bfr[j], acc[i][j], 0, 0, 0);
    __syncthreads();                 // all reads done before next staging
  }

  // epilogue: D row = wm+i*16+q*4+t (M), col = wn+j*16+r (N)
#pragma unroll
  for (int i = 0; i < 4; ++i) {
#pragma unroll
    for (int j = 0; j < 4; ++j) {
#pragma unroll
      for (int t = 0; t < 4; ++t) {
        const int row = m0 + wm + i * 16 + q * 4 + t;
        const int col = n0 + wn + j * 16 + r;
        const size_t idx = (size_t)row * N + col;
        float v = acc[i][j][t];
        if (EPI == 1) {
          ((u16*)Cp)[idx] = f2bf(v);
        } else if (EPI == 2) {           // dt = softplus(v + b_dt)
          v += bf2f(bias[col]);
          v = (v > 15.f) ? v : __logf(1.f + __expf(v));
          ((u16*)Cp)[idx] = f2bf(v);
        } else if (EPI == 3) {           // h = x + mamba_out (f32)
          v += fl ? addf[idx] : bf2f(addbf[idx]);
          ((float*)Cp)[idx] = v;
        } else if (EPI == 4) {           // relu(v + b1)
          v += bf2f(bias[col]);
          ((u16*)Cp)[idx] = f2bf(fmaxf(v, 0.f));
        } else {                         // out = h + v + b2
          v += bf2f(bias[col]) + addf[idx];
          if (fl) ((float*)Cp)[idx] = v;
          else    ((u16*)Cp)[idx] = f2bf(v);
        }
      }
    }
  }
}

// ---------------------------------------------------------------------------
// x_proj split-K: part[z] = u[:, z*256:(z+1)*256] @ w_xproj[:, same]^T
// grid (8, 64): z = K-chunk, y = M-block. N=68 (B rows clamped; cols>=68 junk,
// never stored). Output f32 partials [8, NTOK, 68].
// ---------------------------------------------------------------------------
__global__ __launch_bounds__(256, 2)
void xproj_splitk(const u16* __restrict__ A, const u16* __restrict__ B,
                  float* __restrict__ part)
{
  __shared__ __align__(16) u16 sA[128 * 32];
  __shared__ __align__(16) u16 sB[128 * 32];
  const int tid = threadIdx.x;
  const int kz = blockIdx.x;           // 0..7
  const int m0 = blockIdx.y * 128;
  const int kbase = kz * 256;
  const int lane = tid & 63;
  const int wv = tid >> 6;
  const int wm = (wv & 1) * 64;
  const int wn = (wv >> 1) * 64;
  const int r = lane & 15;
  const int q = lane >> 4;
  const int pr = lane >> 2;
  const int pk = (lane & 3) * 8;

  u16* lA0 = &sA[(wv * 2 + 0) * 512];
  u16* lA1 = &sA[(wv * 2 + 1) * 512];
  u16* lB0 = &sB[(wv * 2 + 0) * 512];
  u16* lB1 = &sB[(wv * 2 + 1) * 512];
  int br0 = wv * 32 + pr;      if (br0 > 67) br0 = 67;   // clamp: junk cols unused
  int br1 = wv * 32 + 16 + pr; if (br1 > 67) br1 = 67;
  const u16* gA0 = A + (size_t)(m0 + wv * 32 + pr) * DI + kbase + pk;
  const u16* gA1 = gA0 + (size_t)16 * DI;
  const u16* gB0 = B + (size_t)br0 * DI + kbase + pk;
  const u16* gB1 = B + (size_t)br1 * DI + kbase + pk;

  f32x4 acc[4][4];
#pragma unroll
  for (int i = 0; i < 4; ++i)
#pragma unroll
    for (int j = 0; j < 4; ++j)
#pragma unroll
      for (int t = 0; t < 4; ++t) acc[i][j][t] = 0.f;

  for (int kt = 0; kt < 8; ++kt) {
    g2l16(gA0, lA0); g2l16(gA1, lA1);
    g2l16(gB0, lB0); g2l16(gB1, lB1);
    gA0 += 32; gA1 += 32; gB0 += 32; gB1 += 32;
    __syncthreads();
    bf16x8 af[4], bfr[4];
#pragma unroll
    for (int i = 0; i < 4; ++i)
      af[i] = *reinterpret_cast<const bf16x8*>(&sA[(wm + i * 16 + r) * 32 + q * 8]);
#pragma unroll
    for (int j = 0; j < 4; ++j)
      bfr[j] = *reinterpret_cast<const bf16x8*>(&sB[(wn + j * 16 + r) * 32 + q * 8]);
#pragma unroll
    for (int i = 0; i < 4; ++i)
#pragma unroll
      for (int j = 0; j < 4; ++j)
        acc[i][j] = __builtin_amdgcn_mfma_f32_16x16x32_bf16(af[i], bfr[j], acc[i][j], 0, 0, 0);
    __syncthreads();
  }

#pragma unroll
  for (int i = 0; i < 4; ++i)
#pragma unroll
    for (int j = 0; j < 4; ++j)
#pragma unroll
      for (int t = 0; t < 4; ++t) {
        const int row = m0 + wm + i * 16 + q * 4 + t;
        const int col = wn + j * 16 + r;
        if (col < NXP)
          part[((size_t)kz * NTOK + row) * NXP + col] = acc[i][j][t];
      }
}

// Reduce partials: cols 0..63 -> dtraw bf16 [NTOK,64]; 64..67 -> bc f32 [NTOK,4]
__global__ __launch_bounds__(256)
void xreduce_kernel(const float* __restrict__ part, u16* __restrict__ dtraw,
                    float* __restrict__ bc)
{
  const int i = blockIdx.x * 256 + threadIdx.x;
  if (i >= NTOK * NXP) return;
  const int row = i / NXP, col = i - row * NXP;
  float s = 0.f;
#pragma unroll
  for (int z = 0; z < 8; ++z) s += part[(size_t)z * NTOK * NXP + i];
  if (col < DTR) dtraw[(size_t)row * DTR + col] = f2bf(s);
  else           bc[row * 4 + (col - DTR)] = s;
}

// ---------------------------------------------------------------------------
// Depthwise causal conv (k=4) + bias + SiLU
// ---------------------------------------------------------------------------
__global__ __launch_bounds__(256)
void conv_silu_kernel(const u16* __restrict__ xp, const u16* __restrict__ cw,
                      const u16* __restrict__ cb, u16* __restrict__ u)
{
  const int i = blockIdx.x * 256 + threadIdx.x;   // NTOK*DI
  const int d = i & (DI - 1);
  const int token = i >> 11;
  const int t = token & (SEQ - 1);
  float acc = bf2f(cb[d]);
#pragma unroll
  for (int j = 0; j < 4; ++j) {
    const int tt = t - 3 + j;
    if (tt >= 0)
      acc += bf2f(cw[d * 4 + j]) * bf2f(xp[(size_t)(token - 3 + j) * DI + d]);
  }
  const float sg = 1.f / (1.f + __expf(-acc));
  u[i] = f2bf(acc * sg);
}

// ---------------------------------------------------------------------------
// Chunked SSM scan (N=2 states)
// ---------------------------------------------------------------------------
__global__ __launch_bounds__(256)
void scan_pass1(const u16* __restrict__ dtb, const u16* __restrict__ ub,
                const float* __restrict__ bc, const u16* __restrict__ a_log,
                float* __restrict__ S, float* __restrict__ hf0, float* __restrict__ hf1)
{
  const int g = blockIdx.x * 256 + threadIdx.x;   // NCHK*NCH
  const int ch = g & (NCH - 1);
  const int c = g >> 12;
  const int b = ch >> 11;
  const int d = ch & (DI - 1);
  const float A0 = -__expf(bf2f(a_log[d * 2 + 0]));
  const float A1 = -__expf(bf2f(a_log[d * 2 + 1]));
  float h0 = 0.f, h1 = 0.f, s = 0.f;
  const int row0 = b * SEQ + c * CHUNK;
  for (int i = 0; i < CHUNK; ++i) {
    const size_t row = row0 + i;
    const float dt = bf2f(dtb[row * DI + d]);
    const float uu = bf2f(ub[row * DI + d]);
    const float B0 = bc[row * 4 + 0];
    const float B1 = bc[row * 4 + 1];
    const float dtu = dt * uu;
    h0 = __expf(A0 * dt) * h0 + dtu * B0;
    h1 = __expf(A1 * dt) * h1 + dtu * B1;
    s += dt;
  }
  S[g] = s; hf0[g] = h0; hf1[g] = h1;
}

__global__ __launch_bounds__(256)
void scan_pass2(const float* __restrict__ S, const float* __restrict__ hf0,
                const float* __restrict__ hf1, const u16* __restrict__ a_log,
                float* __restrict__ hi0, float* __restrict__ hi1)
{
  const int ch = blockIdx.x * 256 + threadIdx.x;  // NCH
  const int d = ch & (DI - 1);
  const float A0 = -__expf(bf2f(a_log[d * 2 + 0]));
  const float A1 = -__expf(bf2f(a_log[d * 2 + 1]));
  float h0 = 0.f, h1 = 0.f;
  for (int c = 0; c < NCHK; ++c) {
    const int g = c * NCH + ch;
    hi0[g] = h0; hi1[g] = h1;
    const float s = S[g];
    h0 = __expf(A0 * s) * h0 + hf0[g];
    h1 = __expf(A1 * s) * h1 + hf1[g];
  }
}

__global__ __launch_bounds__(256)
void scan_pass3(const u16* __restrict__ dtb, const u16* __restrict__ ub,
                const float* __restrict__ bc, const u16* __restrict__ zbuf,
                const u16* __restrict__ a_log, const u16* __restrict__ d_skip,
                const float* __restrict__ hi0, const float* __restrict__ hi1,
                u16* __restrict__ yb)
{
  const int g = blockIdx.x * 256 + threadIdx.x;
  const int ch = g & (NCH - 1);
  const int c = g >> 12;
  const int b = ch >> 11;
  const int d = ch & (DI - 1);
  const float A0 = -__expf(bf2f(a_log[d * 2 + 0]));
  const float A1 = -__expf(bf2f(a_log[d * 2 + 1]));
  const float dsk = bf2f(d_skip[d]);
  float h0 = hi0[g], h1 = hi1[g];
  const int row0 = b * SEQ + c * CHUNK;
  for (int i = 0; i < CHUNK; ++i) {
    const size_t row = row0 + i;
    const float dt = bf2f(dtb[row * DI + d]);
    const float uu = bf2f(ub[row * DI + d]);
    const float B0 = bc[row * 4 + 0];
    const float B1 = bc[row * 4 + 1];
    const float C0 = bc[row * 4 + 2];
    const float C1 = bc[row * 4 + 3];
    const float dtu = dt * uu;
    h0 = __expf(A0 * dt) * h0 + dtu * B0;
    h1 = __expf(A1 * dt) * h1 + dtu * B1;
    const float y = h0 * C0 + h1 * C1;
    const float z = bf2f(zbuf[row * DI + d]);
    const float sz = z / (1.f + __expf(-z));
    yb[row * DI + d] = f2bf((y + dsk * uu) * sz);   // in-place over dtb: ok
  }
}

// ---------------------------------------------------------------------------
extern "C" void kernel_launch(void* const* d_in, const int* in_sizes, int n_in,
                              void* d_out, int out_size, void* d_ws, size_t ws_size,
                              hipStream_t stream)
{
  const void* x       = d_in[0];
  const void* w_in    = d_in[1];
  const void* conv_w  = d_in[2];
  const void* conv_b  = d_in[3];
  const void* w_xproj = d_in[4];
  const void* w_dt    = d_in[5];
  const void* b_dt    = d_in[6];
  const void* a_log   = d_in[7];
  const void* d_skip  = d_in[8];
  const void* w_out   = d_in[9];
  const void* ln1_g   = d_in[10];
  const void* ln1_b   = d_in[11];
  const void* ln2_g   = d_in[12];
  const void* ln2_b   = d_in[13];
  const void* ffn_w1  = d_in[14];
  const void* ffn_b1  = d_in[15];
  const void* ffn_w2  = d_in[16];
  const void* ffn_b2  = d_in[17];
  char* ws = (char*)d_ws;

  // ---- workspace layout (high-water 134.3 MB, same as round 2) ----
  const size_t o_flag  = 0;
  const size_t o_small = 256;
  const size_t o_cwout = o_small + 65536;                 //  65,792
  const size_t o_cff1  = o_cwout + (size_t)DM * DI * 2;   //   4,260,096
  const size_t o_cff2  = o_cff1  + (size_t)DM * DM * 2;   //   6,357,248
  const size_t o_cxp   = o_cff2  + (size_t)DM * DM * 2;   //   8,454,400
  const size_t o_cwdt  = o_cxp   + (size_t)NXP * DI * 2;  //   8,732,928
  const size_t o_xn    = 9437184;                         //  16 MiB region
  const size_t o_xp    = o_xn + (size_t)NTOK * DM * 2;    //  26,214,400 (32 MiB)
  const size_t o_z     = o_xp + (size_t)NTOK * DI * 2;    //  59,768,832 (32 MiB)
  const size_t o_u     = o_z  + (size_t)NTOK * DI * 2;    //  93,323,264 (32 MiB)
  const size_t o_bc    = o_u  + (size_t)NTOK * DI * 2;    // 126,877,696
  const size_t o_S     = o_bc + (size_t)NTOK * 4 * 4 + 2097152; // 129,105,920
  const size_t o_hf0   = o_S   + (size_t)NCHK * NCH * 4;
  const size_t o_hf1   = o_hf0 + (size_t)NCHK * NCH * 4;
  const size_t o_hi0   = o_hf1 + (size_t)NCHK * NCH * 4;
  const size_t o_hi1   = o_hi0 + (size_t)NCHK * NCH * 4;

  int*   flagp   = (int*)(ws + o_flag);
  u16*   csmall  = (u16*)(ws + o_small);
  u16*   c_convw = csmall +     0;
  u16*   c_convb = csmall +  8192;
  u16*   c_bdt   = csmall + 10240;
  u16*   c_alog  = csmall + 12288;
  u16*   c_dskip = csmall + 16384;
  u16*   c_ln1g  = csmall + 18432;
  u16*   c_ln1b  = csmall + 19456;
  u16*   c_ln2g  = csmall + 20480;
  u16*   c_ln2b  = csmall + 21504;
  u16*   c_fb1   = csmall + 22528;
  u16*   c_fb2   = csmall + 23552;
  u16*   c_wout  = (u16*)(ws + o_cwout);
  u16*   c_ff1   = (u16*)(ws + o_cff1);
  u16*   c_ff2   = (u16*)(ws + o_cff2);
  u16*   c_xproj = (u16*)(ws + o_cxp);
  u16*   c_wdt   = (u16*)(ws + o_cwdt);
  u16*   c_win   = (u16*)(ws + o_u);     // overlays u (dead until conv)
  u16*   xn      = (u16*)(ws + o_xn);
  u16*   xp      = (u16*)(ws + o_xp);
  u16*   zb      = (u16*)(ws + o_z);
  u16*   u       = (u16*)(ws + o_u);
  float* part    = (float*)(ws + o_xp);  // overlays xp (dead after conv) 17.8 MB
  u16*   dtraw   = (u16*)(ws + o_xn);    // overlays xn (dead after in_proj)
  u16*   dtb     = xp;                   // overlays part (dead after reduce)
  u16*   yb      = xp;
  float* bc      = (float*)(ws + o_bc);
  float* S       = (float*)(ws + o_S);
  float* hf0     = (float*)(ws + o_hf0);
  float* hf1     = (float*)(ws + o_hf1);
  float* hi0     = (float*)(ws + o_hi0);
  float* hi1     = (float*)(ws + o_hi1);
  float* h       = (float*)(ws + o_z);   // overlays z (dead after pass3)
  u16*   hn      = (u16*)(ws + o_xn);    // overlays xn/dtraw (dead)
  u16*   f1      = (u16*)(ws + o_u);     // overlays u (dead)

  const dim3 blk(256);

  // 0) detect dtype; normalize params to bf16
  detect_kernel<<<1, blk, 0, stream>>>((const u16*)x, flagp);
  convert_kernel<<<(2 * DI * DM) / 256, blk, 0, stream>>>(w_in, c_win, 2 * DI * DM, flagp);
  convert_kernel<<<(NXP * DI + 255) / 256, blk, 0, stream>>>(w_xproj, c_xproj, NXP * DI, flagp);
  convert_kernel<<<(DI * DTR) / 256, blk, 0, stream>>>(w_dt, c_wdt, DI * DTR, flagp);
  convert_kernel<<<(DM * DI) / 256, blk, 0, stream>>>(w_out, c_wout, DM * DI, flagp);
  convert_kernel<<<(DM * DM) / 256, blk, 0, stream>>>(ffn_w1, c_ff1, DM * DM, flagp);
  convert_kernel<<<(DM * DM) / 256, blk, 0, stream>>>(ffn_w2, c_ff2, DM * DM, flagp);
  convert_small_kernel<<<96, blk, 0, stream>>>(conv_w, conv_b, b_dt, a_log, d_skip,
                                               ln1_g, ln1_b, ln2_g, ln2_b, ffn_b1, ffn_b2,
                                               csmall, flagp);

  // 1) LN1(x) -> xn
  ln_kernel<true><<<NTOK, blk, 0, stream>>>(x, c_ln1g, c_ln1b, xn, flagp);
  // 2) xp = xn @ w_in[:2048]^T ; z = xn @ w_in[2048:]^T   (N=2048 -> LNBX=4)
  gemm_kernel<1, 4><<<1024, blk, 0, stream>>>(xn, c_win, NTOK, DI, DM,
                                              nullptr, nullptr, nullptr, flagp, xp);
  gemm_kernel<1, 4><<<1024, blk, 0, stream>>>(xn, c_win + (size_t)DI * DM, NTOK, DI, DM,
                                              nullptr, nullptr, nullptr, flagp, zb);
  // 3) u = silu(conv(xp) + conv_b)
  conv_silu_kernel<<<NTOK * DI / 256, blk, 0, stream>>>(xp, c_convw, c_convb, u);
  // 4) x_proj split-K (partials) + reduce -> dtraw (bf16), bc (f32)
  xproj_splitk<<<dim3(8, 64), blk, 0, stream>>>(u, c_xproj, part);
  xreduce_kernel<<<(NTOK * NXP + 255) / 256, blk, 0, stream>>>(part, dtraw, bc);
  // 5) dt = softplus(dtraw @ w_dt^T + b_dt)   (N=2048 -> LNBX=4, K=64)
  gemm_kernel<2, 4><<<1024, blk, 0, stream>>>(dtraw, c_wdt, NTOK, DI, DTR,
                                              c_bdt, nullptr, nullptr, flagp, dtb);
  // 6) chunked scan -> yb = (y + d_skip*u) * silu(z)
  scan_pass1<<<NCHK * NCH / 256, blk, 0, stream>>>(dtb, u, bc, c_alog, S, hf0, hf1);
  scan_pass2<<<NCH / 256, blk, 0, stream>>>(S, hf0, hf1, c_alog, hi0, hi1);
  scan_pass3<<<NCHK * NCH / 256, blk, 0, stream>>>(dtb, u, bc, zb, c_alog, c_dskip,
                                                   hi0, hi1, yb);
  // 7) h = x + yb @ w_out^T   (N=1024 -> LNBX=3)
  gemm_kernel<3, 3><<<512, blk, 0, stream>>>(yb, c_wout, NTOK, DM, DI,
                                             nullptr, (const u16*)x, (const float*)x,
                                             flagp, h);
  // 8) LN2(h) -> hn
  ln_kernel<false><<<NTOK, blk, 0, stream>>>(h, c_ln2g, c_ln2b, hn, flagp);
  // 9) f1 = relu(hn @ ffn_w1^T + b1)
  gemm_kernel<4, 3><<<512, blk, 0, stream>>>(hn, c_ff1, NTOK, DM, DM,
                                             c_fb1, nullptr, nullptr, flagp, f1);
  // 10) out = h + f1 @ ffn_w2^T + b2
  gemm_kernel<5, 3><<<512, blk, 0, stream>>>(f1, c_ff2, NTOK, DM, DM,
                                             c_fb2, nullptr, h, flagp, d_out);
}

// Round 4
// 517.744 us; speedup vs baseline: 1.2791x; 1.0129x over previous
//
#include <hip/hip_runtime.h>

typedef unsigned short u16;
typedef __bf16 bf16x8 __attribute__((ext_vector_type(8)));
typedef float f32x4 __attribute__((ext_vector_type(4)));

// Problem constants
#define SEQ   4096
#define DM    1024
#define DI    2048
#define NTOK  8192      // BATCH * SEQ
#define NXP   68        // DT_RANK + 2*D_STATE
#define DTR   64        // DT_RANK
#define NCH   4096      // BATCH * DI channels for scan
#define CHUNK 64
#define NCHK  64        // SEQ / CHUNK

__device__ __forceinline__ float bf2f(u16 v) {
  union { unsigned u; float f; } x; x.u = ((unsigned)v) << 16; return x.f;
}
__device__ __forceinline__ u16 f2bf(float f) {
  unsigned u = __float_as_uint(f);
  return (u16)((u + 0x7FFFu + ((u >> 16) & 1u)) >> 16);   // RNE
}

// async global->LDS DMA, 16B/lane; LDS dest = wave-uniform base + lane*16
__device__ __forceinline__ void g2l16(const u16* g, u16* l) {
  __builtin_amdgcn_global_load_lds(
      (const __attribute__((address_space(1))) unsigned int*)g,
      (__attribute__((address_space(3))) unsigned int*)l, 16, 0, 0);
}

// ---------------------------------------------------------------------------
// Input dtype detection (f32 inputs -> low u16 has huge bf16 exponents)
// ---------------------------------------------------------------------------
__global__ __launch_bounds__(256)
void detect_kernel(const u16* __restrict__ x, int* __restrict__ flag)
{
  __shared__ int tot;
  if (threadIdx.x == 0) tot = 0;
  __syncthreads();
  int cnt = 0;
  for (int i = threadIdx.x; i < 4096; i += 256) {
    const int e = (x[2 * i] >> 7) & 0xFF;
    if (e > 167) cnt++;
  }
  atomicAdd(&tot, cnt);
  __syncthreads();
  if (threadIdx.x == 0) flag[0] = (tot >= 8) ? 1 : 0;
}

__global__ __launch_bounds__(256)
void convert_kernel(const void* __restrict__ src, u16* __restrict__ dst, int n,
                    const int* __restrict__ flag)
{
  const int i = blockIdx.x * 256 + threadIdx.x;
  if (i < n)
    dst[i] = (*flag) ? f2bf(((const float*)src)[i]) : ((const u16*)src)[i];
}

__global__ __launch_bounds__(256)
void convert_small_kernel(const void* s0, const void* s1, const void* s2,
                          const void* s3, const void* s4, const void* s5,
                          const void* s6, const void* s7, const void* s8,
                          const void* s9, const void* s10,
                          u16* __restrict__ dst, const int* __restrict__ flag)
{
  const int i = blockIdx.x * 256 + threadIdx.x;
  if (i >= 24576) return;
  const void* src; int off;
  if      (i < 8192)  { src = s0;  off = i; }          // conv_w  [2048*4]
  else if (i < 10240) { src = s1;  off = i - 8192; }   // conv_b
  else if (i < 12288) { src = s2;  off = i - 10240; }  // b_dt
  else if (i < 16384) { src = s3;  off = i - 12288; }  // a_log
  else if (i < 18432) { src = s4;  off = i - 16384; }  // d_skip
  else if (i < 19456) { src = s5;  off = i - 18432; }  // ln1_g
  else if (i < 20480) { src = s6;  off = i - 19456; }  // ln1_b
  else if (i < 21504) { src = s7;  off = i - 20480; }  // ln2_g
  else if (i < 22528) { src = s8;  off = i - 21504; }  // ln2_b
  else if (i < 23552) { src = s9;  off = i - 22528; }  // ffn_b1
  else                { src = s10; off = i - 23552; }  // ffn_b2
  dst[i] = (*flag) ? f2bf(((const float*)src)[off]) : ((const u16*)src)[off];
}

// ---------------------------------------------------------------------------
// LayerNorm over rows of 1024 -> bf16
// ---------------------------------------------------------------------------
template<bool DUAL>
__global__ __launch_bounds__(256)
void ln_kernel(const void* __restrict__ xin, const u16* __restrict__ gw,
               const u16* __restrict__ bw, u16* __restrict__ outp,
               const int* __restrict__ flag)
{
  const int row = blockIdx.x;
  const int tid = threadIdx.x;
  const bool isf32 = DUAL ? (*flag != 0) : true;
  const float* xf = (const float*)xin;
  const u16*   xb = (const u16*)xin;
  float v[4];
#pragma unroll
  for (int k = 0; k < 4; ++k) {
    size_t idx = (size_t)row * DM + tid + k * 256;
    v[k] = isf32 ? xf[idx] : bf2f(xb[idx]);
  }
  float s = v[0] + v[1] + v[2] + v[3];
  float s2 = v[0]*v[0] + v[1]*v[1] + v[2]*v[2] + v[3]*v[3];
#pragma unroll
  for (int off = 32; off > 0; off >>= 1) {
    s  += __shfl_down(s,  off);
    s2 += __shfl_down(s2, off);
  }
  __shared__ float red[8];
  const int wv = tid >> 6, lane = tid & 63;
  if (lane == 0) { red[wv] = s; red[4 + wv] = s2; }
  __syncthreads();
  if (tid == 0) {
    float ts = red[0] + red[1] + red[2] + red[3];
    float t2 = red[4] + red[5] + red[6] + red[7];
    float mu = ts * (1.f / DM);
    float var = t2 * (1.f / DM) - mu * mu;
    red[0] = mu; red[1] = rsqrtf(var + 1e-5f);
  }
  __syncthreads();
  const float mu = red[0], rs = red[1];
#pragma unroll
  for (int k = 0; k < 4; ++k) {
    int col = tid + k * 256;
    size_t idx = (size_t)row * DM + col;
    outp[idx] = f2bf((v[k] - mu) * rs * bf2f(gw[col]) + bf2f(bw[col]));
  }
}

// ---------------------------------------------------------------------------
// bf16 MFMA GEMM: C[M,N] = A[M,K] @ B[N,K]^T.  128x128 tile, BK=32,
// double-buffered LDS, 1-deep global_load_lds prefetch, ONE barrier/iter,
// XCD swizzle (8 y-bands, sweep x in-band).
// Requires: M%128==0, N%128==0, K%32==0, gridDim.x == (N/128)*64, N/128==1<<LNBX.
// EPI: 1 bf16 | 2 +bias,softplus->bf16 | 3 +x(flag dtype)->f32 |
//      4 +bias,relu->bf16 | 5 +bias+addf32 -> out(bf16/f32 per flag)
// ---------------------------------------------------------------------------
template<int EPI, int LNBX>
__global__ __launch_bounds__(256, 2)
void gemm_kernel(const u16* __restrict__ A, const u16* __restrict__ B,
                 int M, int N, int K,
                 const u16* __restrict__ bias, const u16* __restrict__ addbf,
                 const float* __restrict__ addf, const int* __restrict__ dtflag,
                 void* __restrict__ Cp)
{
  __shared__ __align__(16) u16 sA[2][128 * 32];
  __shared__ __align__(16) u16 sB[2][128 * 32];
  const int tid = threadIdx.x;
  const int b = blockIdx.x;
  const int xcd = b & 7;
  const int kk = b >> 3;
  const int bx = kk & ((1 << LNBX) - 1);
  const int by = xcd * 8 + (kk >> LNBX);
  const int m0 = by * 128;
  const int n0 = bx * 128;
  const int lane = tid & 63;
  const int wv = tid >> 6;
  const int wm = (wv & 1) * 64;
  const int wn = (wv >> 1) * 64;
  const int r = lane & 15;
  const int q = lane >> 4;

  // staging: wave wv DMAs rows [32wv,32wv+32) of each tile as two 16-row chunks
  const int pr = lane >> 2;            // 0..15 row in chunk
  const int pk = (lane & 3) * 8;       // k elem offset 0,8,16,24
  u16* lA0[2] = { &sA[0][(wv * 2 + 0) * 512], &sA[1][(wv * 2 + 0) * 512] };
  u16* lA1[2] = { &sA[0][(wv * 2 + 1) * 512], &sA[1][(wv * 2 + 1) * 512] };
  u16* lB0[2] = { &sB[0][(wv * 2 + 0) * 512], &sB[1][(wv * 2 + 0) * 512] };
  u16* lB1[2] = { &sB[0][(wv * 2 + 1) * 512], &sB[1][(wv * 2 + 1) * 512] };
  const u16* gA0 = A + (size_t)(m0 + wv * 32 + pr) * K + pk;
  const u16* gA1 = gA0 + (size_t)16 * K;
  const u16* gB0 = B + (size_t)(n0 + wv * 32 + pr) * K + pk;
  const u16* gB1 = gB0 + (size_t)16 * K;

  const int fl = (EPI == 3 || EPI == 5) ? *dtflag : 0;

  f32x4 acc[4][4];
#pragma unroll
  for (int i = 0; i < 4; ++i)
#pragma unroll
    for (int j = 0; j < 4; ++j)
#pragma unroll
      for (int t = 0; t < 4; ++t) acc[i][j][t] = 0.f;

  // prologue: stage tile 0 into buffer 0
  g2l16(gA0, lA0[0]); g2l16(gA1, lA1[0]);
  g2l16(gB0, lB0[0]); g2l16(gB1, lB1[0]);

  const int nk = K >> 5;
  for (int kt = 0; kt < nk; ++kt) {
    const int cur = kt & 1;
    __syncthreads();   // drains vmcnt(0): tile-kt deposits complete (all waves)
    bf16x8 af[4], bfr[4];
#pragma unroll
    for (int i = 0; i < 4; ++i)
      af[i] = *reinterpret_cast<const bf16x8*>(&sA[cur][(wm + i * 16 + r) * 32 + q * 8]);
#pragma unroll
    for (int j = 0; j < 4; ++j)
      bfr[j] = *reinterpret_cast<const bf16x8*>(&sB[cur][(wn + j * 16 + r) * 32 + q * 8]);
    if (kt + 1 < nk) {   // prefetch tile kt+1 into other buffer; in flight
      gA0 += 32; gA1 += 32; gB0 += 32; gB1 += 32;   // across the MFMAs below
      g2l16(gA0, lA0[cur ^ 1]); g2l16(gA1, lA1[cur ^ 1]);
      g2l16(gB0, lB0[cur ^ 1]); g2l16(gB1, lB1[cur ^ 1]);
    }
#pragma unroll
    for (int i = 0; i < 4; ++i)
#pragma unroll
      for (int j = 0; j < 4; ++j)
        acc[i][j] = __builtin_amdgcn_mfma_f32_16x16x32_bf16(af[i], bfr[j], acc[i][j], 0, 0, 0);
  }

  // epilogue: D row = wm+i*16+q*4+t (M), col = wn+j*16+r (N)
#pragma unroll
  for (int i = 0; i < 4; ++i) {
#pragma unroll
    for (int j = 0; j < 4; ++j) {
#pragma unroll
      for (int t = 0; t < 4; ++t) {
        const int row = m0 + wm + i * 16 + q * 4 + t;
        const int col = n0 + wn + j * 16 + r;
        const size_t idx = (size_t)row * N + col;
        float v = acc[i][j][t];
        if (EPI == 1) {
          ((u16*)Cp)[idx] = f2bf(v);
        } else if (EPI == 2) {           // dt = softplus(v + b_dt)
          v += bf2f(bias[col]);
          v = (v > 15.f) ? v : __logf(1.f + __expf(v));
          ((u16*)Cp)[idx] = f2bf(v);
        } else if (EPI == 3) {           // h = x + mamba_out (f32)
          v += fl ? addf[idx] : bf2f(addbf[idx]);
          ((float*)Cp)[idx] = v;
        } else if (EPI == 4) {           // relu(v + b1)
          v += bf2f(bias[col]);
          ((u16*)Cp)[idx] = f2bf(fmaxf(v, 0.f));
        } else {                         // out = h + v + b2
          v += bf2f(bias[col]) + addf[idx];
          if (fl) ((float*)Cp)[idx] = v;
          else    ((u16*)Cp)[idx] = f2bf(v);
        }
      }
    }
  }
}

// ---------------------------------------------------------------------------
// x_proj split-K: part[z] = u[:, z*256:(z+1)*256] @ w_xproj[:, same]^T
// grid (8, 64): z = K-chunk, y = M-block. N=68 (B rows clamped; cols>=68 junk,
// never stored). Output f32 partials [8, NTOK, 68]. Same dbuf pipeline.
// ---------------------------------------------------------------------------
__global__ __launch_bounds__(256, 2)
void xproj_splitk(const u16* __restrict__ A, const u16* __restrict__ B,
                  float* __restrict__ part)
{
  __shared__ __align__(16) u16 sA[2][128 * 32];
  __shared__ __align__(16) u16 sB[2][128 * 32];
  const int tid = threadIdx.x;
  const int kz = blockIdx.x;           // 0..7
  const int m0 = blockIdx.y * 128;
  const int kbase = kz * 256;
  const int lane = tid & 63;
  const int wv = tid >> 6;
  const int wm = (wv & 1) * 64;
  const int wn = (wv >> 1) * 64;
  const int r = lane & 15;
  const int q = lane >> 4;
  const int pr = lane >> 2;
  const int pk = (lane & 3) * 8;

  u16* lA0[2] = { &sA[0][(wv * 2 + 0) * 512], &sA[1][(wv * 2 + 0) * 512] };
  u16* lA1[2] = { &sA[0][(wv * 2 + 1) * 512], &sA[1][(wv * 2 + 1) * 512] };
  u16* lB0[2] = { &sB[0][(wv * 2 + 0) * 512], &sB[1][(wv * 2 + 0) * 512] };
  u16* lB1[2] = { &sB[0][(wv * 2 + 1) * 512], &sB[1][(wv * 2 + 1) * 512] };
  int br0 = wv * 32 + pr;      if (br0 > 67) br0 = 67;   // clamp: junk cols unused
  int br1 = wv * 32 + 16 + pr; if (br1 > 67) br1 = 67;
  const u16* gA0 = A + (size_t)(m0 + wv * 32 + pr) * DI + kbase + pk;
  const u16* gA1 = gA0 + (size_t)16 * DI;
  const u16* gB0 = B + (size_t)br0 * DI + kbase + pk;
  const u16* gB1 = B + (size_t)br1 * DI + kbase + pk;

  f32x4 acc[4][4];
#pragma unroll
  for (int i = 0; i < 4; ++i)
#pragma unroll
    for (int j = 0; j < 4; ++j)
#pragma unroll
      for (int t = 0; t < 4; ++t) acc[i][j][t] = 0.f;

  g2l16(gA0, lA0[0]); g2l16(gA1, lA1[0]);
  g2l16(gB0, lB0[0]); g2l16(gB1, lB1[0]);

  for (int kt = 0; kt < 8; ++kt) {
    const int cur = kt & 1;
    __syncthreads();
    bf16x8 af[4], bfr[4];
#pragma unroll
    for (int i = 0; i < 4; ++i)
      af[i] = *reinterpret_cast<const bf16x8*>(&sA[cur][(wm + i * 16 + r) * 32 + q * 8]);
#pragma unroll
    for (int j = 0; j < 4; ++j)
      bfr[j] = *reinterpret_cast<const bf16x8*>(&sB[cur][(wn + j * 16 + r) * 32 + q * 8]);
    if (kt + 1 < 8) {
      gA0 += 32; gA1 += 32; gB0 += 32; gB1 += 32;
      g2l16(gA0, lA0[cur ^ 1]); g2l16(gA1, lA1[cur ^ 1]);
      g2l16(gB0, lB0[cur ^ 1]); g2l16(gB1, lB1[cur ^ 1]);
    }
#pragma unroll
    for (int i = 0; i < 4; ++i)
#pragma unroll
      for (int j = 0; j < 4; ++j)
        acc[i][j] = __builtin_amdgcn_mfma_f32_16x16x32_bf16(af[i], bfr[j], acc[i][j], 0, 0, 0);
  }

#pragma unroll
  for (int i = 0; i < 4; ++i)
#pragma unroll
    for (int j = 0; j < 4; ++j)
#pragma unroll
      for (int t = 0; t < 4; ++t) {
        const int row = m0 + wm + i * 16 + q * 4 + t;
        const int col = wn + j * 16 + r;
        if (col < NXP)
          part[((size_t)kz * NTOK + row) * NXP + col] = acc[i][j][t];
      }
}

// Reduce partials: cols 0..63 -> dtraw bf16 [NTOK,64]; 64..67 -> bc f32 [NTOK,4]
__global__ __launch_bounds__(256)
void xreduce_kernel(const float* __restrict__ part, u16* __restrict__ dtraw,
                    float* __restrict__ bc)
{
  const int i = blockIdx.x * 256 + threadIdx.x;
  if (i >= NTOK * NXP) return;
  const int row = i / NXP, col = i - row * NXP;
  float s = 0.f;
#pragma unroll
  for (int z = 0; z < 8; ++z) s += part[(size_t)z * NTOK * NXP + i];
  if (col < DTR) dtraw[(size_t)row * DTR + col] = f2bf(s);
  else           bc[row * 4 + (col - DTR)] = s;
}

// ---------------------------------------------------------------------------
// Depthwise causal conv (k=4) + bias + SiLU
// ---------------------------------------------------------------------------
__global__ __launch_bounds__(256)
void conv_silu_kernel(const u16* __restrict__ xp, const u16* __restrict__ cw,
                      const u16* __restrict__ cb, u16* __restrict__ u)
{
  const int i = blockIdx.x * 256 + threadIdx.x;   // NTOK*DI
  const int d = i & (DI - 1);
  const int token = i >> 11;
  const int t = token & (SEQ - 1);
  float acc = bf2f(cb[d]);
#pragma unroll
  for (int j = 0; j < 4; ++j) {
    const int tt = t - 3 + j;
    if (tt >= 0)
      acc += bf2f(cw[d * 4 + j]) * bf2f(xp[(size_t)(token - 3 + j) * DI + d]);
  }
  const float sg = 1.f / (1.f + __expf(-acc));
  u[i] = f2bf(acc * sg);
}

// ---------------------------------------------------------------------------
// Chunked SSM scan (N=2 states)
// ---------------------------------------------------------------------------
__global__ __launch_bounds__(256)
void scan_pass1(const u16* __restrict__ dtb, const u16* __restrict__ ub,
                const float* __restrict__ bc, const u16* __restrict__ a_log,
                float* __restrict__ S, float* __restrict__ hf0, float* __restrict__ hf1)
{
  const int g = blockIdx.x * 256 + threadIdx.x;   // NCHK*NCH
  const int ch = g & (NCH - 1);
  const int c = g >> 12;
  const int b = ch >> 11;
  const int d = ch & (DI - 1);
  const float A0 = -__expf(bf2f(a_log[d * 2 + 0]));
  const float A1 = -__expf(bf2f(a_log[d * 2 + 1]));
  float h0 = 0.f, h1 = 0.f, s = 0.f;
  const int row0 = b * SEQ + c * CHUNK;
  for (int i = 0; i < CHUNK; ++i) {
    const size_t row = row0 + i;
    const float dt = bf2f(dtb[row * DI + d]);
    const float uu = bf2f(ub[row * DI + d]);
    const float B0 = bc[row * 4 + 0];
    const float B1 = bc[row * 4 + 1];
    const float dtu = dt * uu;
    h0 = __expf(A0 * dt) * h0 + dtu * B0;
    h1 = __expf(A1 * dt) * h1 + dtu * B1;
    s += dt;
  }
  S[g] = s; hf0[g] = h0; hf1[g] = h1;
}

__global__ __launch_bounds__(256)
void scan_pass2(const float* __restrict__ S, const float* __restrict__ hf0,
                const float* __restrict__ hf1, const u16* __restrict__ a_log,
                float* __restrict__ hi0, float* __restrict__ hi1)
{
  const int ch = blockIdx.x * 256 + threadIdx.x;  // NCH
  const int d = ch & (DI - 1);
  const float A0 = -__expf(bf2f(a_log[d * 2 + 0]));
  const float A1 = -__expf(bf2f(a_log[d * 2 + 1]));
  float h0 = 0.f, h1 = 0.f;
  for (int c = 0; c < NCHK; ++c) {
    const int g = c * NCH + ch;
    hi0[g] = h0; hi1[g] = h1;
    const float s = S[g];
    h0 = __expf(A0 * s) * h0 + hf0[g];
    h1 = __expf(A1 * s) * h1 + hf1[g];
  }
}

__global__ __launch_bounds__(256)
void scan_pass3(const u16* __restrict__ dtb, const u16* __restrict__ ub,
                const float* __restrict__ bc, const u16* __restrict__ zbuf,
                const u16* __restrict__ a_log, const u16* __restrict__ d_skip,
                const float* __restrict__ hi0, const float* __restrict__ hi1,
                u16* __restrict__ yb)
{
  const int g = blockIdx.x * 256 + threadIdx.x;
  const int ch = g & (NCH - 1);
  const int c = g >> 12;
  const int b = ch >> 11;
  const int d = ch & (DI - 1);
  const float A0 = -__expf(bf2f(a_log[d * 2 + 0]));
  const float A1 = -__expf(bf2f(a_log[d * 2 + 1]));
  const float dsk = bf2f(d_skip[d]);
  float h0 = hi0[g], h1 = hi1[g];
  const int row0 = b * SEQ + c * CHUNK;
  for (int i = 0; i < CHUNK; ++i) {
    const size_t row = row0 + i;
    const float dt = bf2f(dtb[row * DI + d]);
    const float uu = bf2f(ub[row * DI + d]);
    const float B0 = bc[row * 4 + 0];
    const float B1 = bc[row * 4 + 1];
    const float C0 = bc[row * 4 + 2];
    const float C1 = bc[row * 4 + 3];
    const float dtu = dt * uu;
    h0 = __expf(A0 * dt) * h0 + dtu * B0;
    h1 = __expf(A1 * dt) * h1 + dtu * B1;
    const float y = h0 * C0 + h1 * C1;
    const float z = bf2f(zbuf[row * DI + d]);
    const float sz = z / (1.f + __expf(-z));
    yb[row * DI + d] = f2bf((y + dsk * uu) * sz);   // in-place over dtb: ok
  }
}

// ---------------------------------------------------------------------------
extern "C" void kernel_launch(void* const* d_in, const int* in_sizes, int n_in,
                              void* d_out, int out_size, void* d_ws, size_t ws_size,
                              hipStream_t stream)
{
  const void* x       = d_in[0];
  const void* w_in    = d_in[1];
  const void* conv_w  = d_in[2];
  const void* conv_b  = d_in[3];
  const void* w_xproj = d_in[4];
  const void* w_dt    = d_in[5];
  const void* b_dt    = d_in[6];
  const void* a_log   = d_in[7];
  const void* d_skip  = d_in[8];
  const void* w_out   = d_in[9];
  const void* ln1_g   = d_in[10];
  const void* ln1_b   = d_in[11];
  const void* ln2_g   = d_in[12];
  const void* ln2_b   = d_in[13];
  const void* ffn_w1  = d_in[14];
  const void* ffn_b1  = d_in[15];
  const void* ffn_w2  = d_in[16];
  const void* ffn_b2  = d_in[17];
  char* ws = (char*)d_ws;

  // ---- workspace layout (high-water ~134.3 MB) ----
  const size_t o_flag  = 0;
  const size_t o_small = 256;
  const size_t o_cwout = o_small + 65536;                 //  65,792
  const size_t o_cff1  = o_cwout + (size_t)DM * DI * 2;   //   4,260,096
  const size_t o_cff2  = o_cff1  + (size_t)DM * DM * 2;   //   6,357,248
  const size_t o_cxp   = o_cff2  + (size_t)DM * DM * 2;   //   8,454,400
  const size_t o_cwdt  = o_cxp   + (size_t)NXP * DI * 2;  //   8,732,928
  const size_t o_xn    = 9437184;                         //  16 MiB region
  const size_t o_xp    = o_xn + (size_t)NTOK * DM * 2;    //  26,214,400 (32 MiB)
  const size_t o_z     = o_xp + (size_t)NTOK * DI * 2;    //  59,768,832 (32 MiB)
  const size_t o_u     = o_z  + (size_t)NTOK * DI * 2;    //  93,323,264 (32 MiB)
  const size_t o_bc    = o_u  + (size_t)NTOK * DI * 2;    // 126,877,696
  const size_t o_S     = o_bc + (size_t)NTOK * 4 * 4 + 2097152; // 129,105,920
  const size_t o_hf0   = o_S   + (size_t)NCHK * NCH * 4;
  const size_t o_hf1   = o_hf0 + (size_t)NCHK * NCH * 4;
  const size_t o_hi0   = o_hf1 + (size_t)NCHK * NCH * 4;
  const size_t o_hi1   = o_hi0 + (size_t)NCHK * NCH * 4;

  int*   flagp   = (int*)(ws + o_flag);
  u16*   csmall  = (u16*)(ws + o_small);
  u16*   c_convw = csmall +     0;
  u16*   c_convb = csmall +  8192;
  u16*   c_bdt   = csmall + 10240;
  u16*   c_alog  = csmall + 12288;
  u16*   c_dskip = csmall + 16384;
  u16*   c_ln1g  = csmall + 18432;
  u16*   c_ln1b  = csmall + 19456;
  u16*   c_ln2g  = csmall + 20480;
  u16*   c_ln2b  = csmall + 21504;
  u16*   c_fb1   = csmall + 22528;
  u16*   c_fb2   = csmall + 23552;
  u16*   c_wout  = (u16*)(ws + o_cwout);
  u16*   c_ff1   = (u16*)(ws + o_cff1);
  u16*   c_ff2   = (u16*)(ws + o_cff2);
  u16*   c_xproj = (u16*)(ws + o_cxp);
  u16*   c_wdt   = (u16*)(ws + o_cwdt);
  u16*   c_win   = (u16*)(ws + o_u);     // overlays u (dead until conv)
  u16*   xn      = (u16*)(ws + o_xn);
  u16*   xp      = (u16*)(ws + o_xp);
  u16*   zb      = (u16*)(ws + o_z);
  u16*   u       = (u16*)(ws + o_u);
  float* part    = (float*)(ws + o_xp);  // overlays xp (dead after conv) 17.8 MB
  u16*   dtraw   = (u16*)(ws + o_xn);    // overlays xn (dead after in_proj)
  u16*   dtb     = xp;                   // overlays part (dead after reduce)
  u16*   yb      = xp;
  float* bc      = (float*)(ws + o_bc);
  float* S       = (float*)(ws + o_S);
  float* hf0     = (float*)(ws + o_hf0);
  float* hf1     = (float*)(ws + o_hf1);
  float* hi0     = (float*)(ws + o_hi0);
  float* hi1     = (float*)(ws + o_hi1);
  float* h       = (float*)(ws + o_z);   // overlays z (dead after pass3)
  u16*   hn      = (u16*)(ws + o_xn);    // overlays xn/dtraw (dead)
  u16*   f1      = (u16*)(ws + o_u);     // overlays u (dead)

  const dim3 blk(256);

  // 0) detect dtype; normalize params to bf16
  detect_kernel<<<1, blk, 0, stream>>>((const u16*)x, flagp);
  convert_kernel<<<(2 * DI * DM) / 256, blk, 0, stream>>>(w_in, c_win, 2 * DI * DM, flagp);
  convert_kernel<<<(NXP * DI + 255) / 256, blk, 0, stream>>>(w_xproj, c_xproj, NXP * DI, flagp);
  convert_kernel<<<(DI * DTR) / 256, blk, 0, stream>>>(w_dt, c_wdt, DI * DTR, flagp);
  convert_kernel<<<(DM * DI) / 256, blk, 0, stream>>>(w_out, c_wout, DM * DI, flagp);
  convert_kernel<<<(DM * DM) / 256, blk, 0, stream>>>(ffn_w1, c_ff1, DM * DM, flagp);
  convert_kernel<<<(DM * DM) / 256, blk, 0, stream>>>(ffn_w2, c_ff2, DM * DM, flagp);
  convert_small_kernel<<<96, blk, 0, stream>>>(conv_w, conv_b, b_dt, a_log, d_skip,
                                               ln1_g, ln1_b, ln2_g, ln2_b, ffn_b1, ffn_b2,
                                               csmall, flagp);

  // 1) LN1(x) -> xn
  ln_kernel<true><<<NTOK, blk, 0, stream>>>(x, c_ln1g, c_ln1b, xn, flagp);
  // 2) xp = xn @ w_in[:2048]^T ; z = xn @ w_in[2048:]^T   (N=2048 -> LNBX=4)
  gemm_kernel<1, 4><<<1024, blk, 0, stream>>>(xn, c_win, NTOK, DI, DM,
                                              nullptr, nullptr, nullptr, flagp, xp);
  gemm_kernel<1, 4><<<1024, blk, 0, stream>>>(xn, c_win + (size_t)DI * DM, NTOK, DI, DM,
                                              nullptr, nullptr, nullptr, flagp, zb);
  // 3) u = silu(conv(xp) + conv_b)
  conv_silu_kernel<<<NTOK * DI / 256, blk, 0, stream>>>(xp, c_convw, c_convb, u);
  // 4) x_proj split-K (partials) + reduce -> dtraw (bf16), bc (f32)
  xproj_splitk<<<dim3(8, 64), blk, 0, stream>>>(u, c_xproj, part);
  xreduce_kernel<<<(NTOK * NXP + 255) / 256, blk, 0, stream>>>(part, dtraw, bc);
  // 5) dt = softplus(dtraw @ w_dt^T + b_dt)   (N=2048 -> LNBX=4, K=64)
  gemm_kernel<2, 4><<<1024, blk, 0, stream>>>(dtraw, c_wdt, NTOK, DI, DTR,
                                              c_bdt, nullptr, nullptr, flagp, dtb);
  // 6) chunked scan -> yb = (y + d_skip*u) * silu(z)
  scan_pass1<<<NCHK * NCH / 256, blk, 0, stream>>>(dtb, u, bc, c_alog, S, hf0, hf1);
  scan_pass2<<<NCH / 256, blk, 0, stream>>>(S, hf0, hf1, c_alog, hi0, hi1);
  scan_pass3<<<NCHK * NCH / 256, blk, 0, stream>>>(dtb, u, bc, zb, c_alog, c_dskip,
                                                   hi0, hi1, yb);
  // 7) h = x + yb @ w_out^T   (N=1024 -> LNBX=3)
  gemm_kernel<3, 3><<<512, blk, 0, stream>>>(yb, c_wout, NTOK, DM, DI,
                                             nullptr, (const u16*)x, (const float*)x,
                                             flagp, h);
  // 8) LN2(h) -> hn
  ln_kernel<false><<<NTOK, blk, 0, stream>>>(h, c_ln2g, c_ln2b, hn, flagp);
  // 9) f1 = relu(hn @ ffn_w1^T + b1)
  gemm_kernel<4, 3><<<512, blk, 0, stream>>>(hn, c_ff1, NTOK, DM, DM,
                                             c_fb1, nullptr, nullptr, flagp, f1);
  // 10) out = h + f1 @ ffn_w2^T + b2
  gemm_kernel<5, 3><<<512, blk, 0, stream>>>(f1, c_ff2, NTOK, DM, DM,
                                             c_fb2, nullptr, h, flagp, d_out);
}

// Round 5
// 503.807 us; speedup vs baseline: 1.3145x; 1.0277x over previous
//
#include <hip/hip_runtime.h>

typedef unsigned short u16;
typedef __bf16 bf16x8 __attribute__((ext_vector_type(8)));
typedef float f32x4 __attribute__((ext_vector_type(4)));
typedef float f32x2 __attribute__((ext_vector_type(2)));
typedef u16 u16x4 __attribute__((ext_vector_type(4)));
typedef u16 u16x8 __attribute__((ext_vector_type(8)));

// Problem constants
#define SEQ   4096
#define DM    1024
#define DI    2048
#define NTOK  8192      // BATCH * SEQ
#define NXP   68        // DT_RANK + 2*D_STATE
#define DTR   64        // DT_RANK
#define NCH   4096      // BATCH * DI channels for scan
#define CHUNK 32
#define NCHK  128       // SEQ / CHUNK

__device__ __forceinline__ float bf2f(u16 v) {
  union { unsigned u; float f; } x; x.u = ((unsigned)v) << 16; return x.f;
}
__device__ __forceinline__ u16 f2bf(float f) {
  unsigned u = __float_as_uint(f);
  return (u16)((u + 0x7FFFu + ((u >> 16) & 1u)) >> 16);   // RNE
}

// async global->LDS DMA, 16B/lane; LDS dest = wave-uniform base + lane*16
__device__ __forceinline__ void g2l16(const u16* g, u16* l) {
  __builtin_amdgcn_global_load_lds(
      (const __attribute__((address_space(1))) unsigned int*)g,
      (__attribute__((address_space(3))) unsigned int*)l, 16, 0, 0);
}

// ---------------------------------------------------------------------------
// Input dtype detection (f32 inputs -> low u16 has huge bf16 exponents)
// ---------------------------------------------------------------------------
__global__ __launch_bounds__(256)
void detect_kernel(const u16* __restrict__ x, int* __restrict__ flag)
{
  __shared__ int tot;
  if (threadIdx.x == 0) tot = 0;
  __syncthreads();
  int cnt = 0;
  for (int i = threadIdx.x; i < 4096; i += 256) {
    const int e = (x[2 * i] >> 7) & 0xFF;
    if (e > 167) cnt++;
  }
  atomicAdd(&tot, cnt);
  __syncthreads();
  if (threadIdx.x == 0) flag[0] = (tot >= 8) ? 1 : 0;
}

// f32 -> bf16 weight copy; NO-OP when inputs are already bf16 (GEMMs then
// read the raw input pointer directly).
__global__ __launch_bounds__(256)
void convert_kernel(const void* __restrict__ src, u16* __restrict__ dst, int n,
                    const int* __restrict__ flag)
{
  if (*flag == 0) return;
  const int i = blockIdx.x * 256 + threadIdx.x;
  if (i < n) dst[i] = f2bf(((const float*)src)[i]);
}

// All 11 small vectors in one launch; conv_w stored TRANSPOSED [4][DI].
__global__ __launch_bounds__(256)
void convert_small_kernel(const void* s0, const void* s1, const void* s2,
                          const void* s3, const void* s4, const void* s5,
                          const void* s6, const void* s7, const void* s8,
                          const void* s9, const void* s10,
                          u16* __restrict__ dst, const int* __restrict__ flag)
{
  const int i = blockIdx.x * 256 + threadIdx.x;
  if (i >= 24576) return;
  const void* src; int off; int dsti = i;
  if      (i < 8192)  { src = s0;  off = i;
                        dsti = (off & 3) * DI + (off >> 2); }  // conv_w -> [j][d]
  else if (i < 10240) { src = s1;  off = i - 8192; }   // conv_b
  else if (i < 12288) { src = s2;  off = i - 10240; }  // b_dt
  else if (i < 16384) { src = s3;  off = i - 12288; }  // a_log
  else if (i < 18432) { src = s4;  off = i - 16384; }  // d_skip
  else if (i < 19456) { src = s5;  off = i - 18432; }  // ln1_g
  else if (i < 20480) { src = s6;  off = i - 19456; }  // ln1_b
  else if (i < 21504) { src = s7;  off = i - 20480; }  // ln2_g
  else if (i < 22528) { src = s8;  off = i - 21504; }  // ln2_b
  else if (i < 23552) { src = s9;  off = i - 22528; }  // ffn_b1
  else                { src = s10; off = i - 23552; }  // ffn_b2
  dst[dsti] = (*flag) ? f2bf(((const float*)src)[off]) : ((const u16*)src)[off];
}

// ---------------------------------------------------------------------------
// LayerNorm: 2 rows per block, 8 elems per thread, vectorized loads/stores.
// ---------------------------------------------------------------------------
template<bool DUAL>
__global__ __launch_bounds__(256)
void ln_kernel(const void* __restrict__ xin, const u16* __restrict__ gw,
               const u16* __restrict__ bw, u16* __restrict__ outp,
               const int* __restrict__ flag)
{
  const int tid = threadIdx.x;
  const int sub = tid >> 7;                  // row within block
  const int col0 = (tid & 127) * 8;
  const int row = blockIdx.x * 2 + sub;
  const bool isf32 = DUAL ? (*flag != 0) : true;
  float v[8];
  if (isf32) {
    const float* xf = (const float*)xin + (size_t)row * DM + col0;
    f32x4 a = *(const f32x4*)xf, b2 = *(const f32x4*)(xf + 4);
#pragma unroll
    for (int k = 0; k < 4; ++k) { v[k] = a[k]; v[4 + k] = b2[k]; }
  } else {
    u16x8 xb = *(const u16x8*)((const u16*)xin + (size_t)row * DM + col0);
#pragma unroll
    for (int k = 0; k < 8; ++k) v[k] = bf2f(xb[k]);
  }
  float s = 0.f, s2 = 0.f;
#pragma unroll
  for (int k = 0; k < 8; ++k) { s += v[k]; s2 += v[k] * v[k]; }
#pragma unroll
  for (int off = 32; off > 0; off >>= 1) {
    s  += __shfl_down(s,  off);
    s2 += __shfl_down(s2, off);
  }
  __shared__ float red[4], red2[4];
  __shared__ f32x2 stat[2];
  const int wv = tid >> 6;
  if ((tid & 63) == 0) { red[wv] = s; red2[wv] = s2; }
  __syncthreads();
  if ((tid & 127) == 0) {
    float ts = red[sub * 2] + red[sub * 2 + 1];
    float t2 = red2[sub * 2] + red2[sub * 2 + 1];
    float mu = ts * (1.f / DM);
    float var = t2 * (1.f / DM) - mu * mu;
    stat[sub] = f32x2{mu, rsqrtf(var + 1e-5f)};
  }
  __syncthreads();
  const float mu = stat[sub][0], rs = stat[sub][1];
  u16x8 gv = *(const u16x8*)(gw + col0), bv = *(const u16x8*)(bw + col0);
  u16x8 o;
#pragma unroll
  for (int k = 0; k < 8; ++k)
    o[k] = f2bf((v[k] - mu) * rs * bf2f(gv[k]) + bf2f(bv[k]));
  *(u16x8*)(outp + (size_t)row * DM + col0) = o;
}

// ---------------------------------------------------------------------------
// bf16 MFMA GEMM: C[M,N] = A[M,K] @ B[N,K]^T.  128x128 tile, BK=32,
// double-buffered LDS, global_load_lds(16B) prefetch, one barrier/iter,
// XCD swizzle. B chosen at runtime: raw input (bf16 case) or converted copy.
// Requires: M%128==0, N%128==0, K%32==0, gridDim.x == (N/128)*64, N/128==1<<LNBX.
// EPI: 1 bf16 | 2 +bias,softplus->bf16 | 3 +x(flag dtype)->f32 |
//      4 +bias,relu->bf16 | 5 +bias+addf32 -> out(bf16/f32 per flag) |
//      6 split store: col<DI -> Cp (bf16), else -> Cp2 (bf16), row stride DI
// ---------------------------------------------------------------------------
template<int EPI, int LNBX>
__global__ __launch_bounds__(256, 2)
void gemm_kernel(const u16* __restrict__ A, const u16* __restrict__ Bc,
                 const u16* __restrict__ Braw,
                 int M, int N, int K,
                 const u16* __restrict__ bias, const u16* __restrict__ addbf,
                 const float* __restrict__ addf, const int* __restrict__ dtflag,
                 void* __restrict__ Cp, void* __restrict__ Cp2)
{
  __shared__ __align__(16) u16 sA[2][128 * 32];
  __shared__ __align__(16) u16 sB[2][128 * 32];
  const int fl = *dtflag;
  const u16* __restrict__ B = fl ? Bc : Braw;
  const int tid = threadIdx.x;
  const int b = blockIdx.x;
  const int xcd = b & 7;
  const int kk = b >> 3;
  const int bx = kk & ((1 << LNBX) - 1);
  const int by = xcd * 8 + (kk >> LNBX);
  const int m0 = by * 128;
  const int n0 = bx * 128;
  const int lane = tid & 63;
  const int wv = tid >> 6;
  const int wm = (wv & 1) * 64;
  const int wn = (wv >> 1) * 64;
  const int r = lane & 15;
  const int q = lane >> 4;

  const int pr = lane >> 2;            // 0..15 row in 16-row staging chunk
  const int pk = (lane & 3) * 8;       // k elem offset 0,8,16,24
  u16* lA0[2] = { &sA[0][(wv * 2 + 0) * 512], &sA[1][(wv * 2 + 0) * 512] };
  u16* lA1[2] = { &sA[0][(wv * 2 + 1) * 512], &sA[1][(wv * 2 + 1) * 512] };
  u16* lB0[2] = { &sB[0][(wv * 2 + 0) * 512], &sB[1][(wv * 2 + 0) * 512] };
  u16* lB1[2] = { &sB[0][(wv * 2 + 1) * 512], &sB[1][(wv * 2 + 1) * 512] };
  const u16* gA0 = A + (size_t)(m0 + wv * 32 + pr) * K + pk;
  const u16* gA1 = gA0 + (size_t)16 * K;
  const u16* gB0 = B + (size_t)(n0 + wv * 32 + pr) * K + pk;
  const u16* gB1 = gB0 + (size_t)16 * K;

  f32x4 acc[4][4];
#pragma unroll
  for (int i = 0; i < 4; ++i)
#pragma unroll
    for (int j = 0; j < 4; ++j)
#pragma unroll
      for (int t = 0; t < 4; ++t) acc[i][j][t] = 0.f;

  g2l16(gA0, lA0[0]); g2l16(gA1, lA1[0]);
  g2l16(gB0, lB0[0]); g2l16(gB1, lB1[0]);

  const int nk = K >> 5;
  for (int kt = 0; kt < nk; ++kt) {
    const int cur = kt & 1;
    __syncthreads();   // drains vmcnt(0): tile-kt deposits complete
    bf16x8 af[4], bfr[4];
#pragma unroll
    for (int i = 0; i < 4; ++i)
      af[i] = *reinterpret_cast<const bf16x8*>(&sA[cur][(wm + i * 16 + r) * 32 + q * 8]);
#pragma unroll
    for (int j = 0; j < 4; ++j)
      bfr[j] = *reinterpret_cast<const bf16x8*>(&sB[cur][(wn + j * 16 + r) * 32 + q * 8]);
    if (kt + 1 < nk) {
      gA0 += 32; gA1 += 32; gB0 += 32; gB1 += 32;
      g2l16(gA0, lA0[cur ^ 1]); g2l16(gA1, lA1[cur ^ 1]);
      g2l16(gB0, lB0[cur ^ 1]); g2l16(gB1, lB1[cur ^ 1]);
    }
#pragma unroll
    for (int i = 0; i < 4; ++i)
#pragma unroll
      for (int j = 0; j < 4; ++j)
        acc[i][j] = __builtin_amdgcn_mfma_f32_16x16x32_bf16(af[i], bfr[j], acc[i][j], 0, 0, 0);
  }

  // epilogue: D row = wm+i*16+q*4+t (M), col = wn+j*16+r (N)
#pragma unroll
  for (int i = 0; i < 4; ++i) {
#pragma unroll
    for (int j = 0; j < 4; ++j) {
#pragma unroll
      for (int t = 0; t < 4; ++t) {
        const int row = m0 + wm + i * 16 + q * 4 + t;
        const int col = n0 + wn + j * 16 + r;
        float v = acc[i][j][t];
        if (EPI == 6) {
          const size_t rb = (size_t)row * DI;
          if (col < DI) ((u16*)Cp)[rb + col] = f2bf(v);
          else          ((u16*)Cp2)[rb + col - DI] = f2bf(v);
        } else {
          const size_t idx = (size_t)row * N + col;
          if (EPI == 1) {
            ((u16*)Cp)[idx] = f2bf(v);
          } else if (EPI == 2) {           // dt = softplus(v + b_dt)
            v += bf2f(bias[col]);
            v = (v > 15.f) ? v : __logf(1.f + __expf(v));
            ((u16*)Cp)[idx] = f2bf(v);
          } else if (EPI == 3) {           // h = x + mamba_out (f32)
            v += fl ? addf[idx] : bf2f(addbf[idx]);
            ((float*)Cp)[idx] = v;
          } else if (EPI == 4) {           // relu(v + b1)
            v += bf2f(bias[col]);
            ((u16*)Cp)[idx] = f2bf(fmaxf(v, 0.f));
          } else {                         // out = h + v + b2
            v += bf2f(bias[col]) + addf[idx];
            if (fl) ((float*)Cp)[idx] = v;
            else    ((u16*)Cp)[idx] = f2bf(v);
          }
        }
      }
    }
  }
}

// ---------------------------------------------------------------------------
// x_proj split-K: part[z] = u[:, z*256:(z+1)*256] @ w_xproj[:, same]^T
// grid (8, 64). Output f32 partials [8, NTOK, 68].
// ---------------------------------------------------------------------------
__global__ __launch_bounds__(256, 2)
void xproj_splitk(const u16* __restrict__ A, const u16* __restrict__ Bc,
                  const u16* __restrict__ Braw, const int* __restrict__ dtflag,
                  float* __restrict__ part)
{
  __shared__ __align__(16) u16 sA[2][128 * 32];
  __shared__ __align__(16) u16 sB[2][128 * 32];
  const int fl = *dtflag;
  const u16* __restrict__ B = fl ? Bc : Braw;
  const int tid = threadIdx.x;
  const int kz = blockIdx.x;           // 0..7
  const int m0 = blockIdx.y * 128;
  const int kbase = kz * 256;
  const int lane = tid & 63;
  const int wv = tid >> 6;
  const int wm = (wv & 1) * 64;
  const int wn = (wv >> 1) * 64;
  const int r = lane & 15;
  const int q = lane >> 4;
  const int pr = lane >> 2;
  const int pk = (lane & 3) * 8;

  u16* lA0[2] = { &sA[0][(wv * 2 + 0) * 512], &sA[1][(wv * 2 + 0) * 512] };
  u16* lA1[2] = { &sA[0][(wv * 2 + 1) * 512], &sA[1][(wv * 2 + 1) * 512] };
  u16* lB0[2] = { &sB[0][(wv * 2 + 0) * 512], &sB[1][(wv * 2 + 0) * 512] };
  u16* lB1[2] = { &sB[0][(wv * 2 + 1) * 512], &sB[1][(wv * 2 + 1) * 512] };
  int br0 = wv * 32 + pr;      if (br0 > 67) br0 = 67;   // junk cols unused
  int br1 = wv * 32 + 16 + pr; if (br1 > 67) br1 = 67;
  const u16* gA0 = A + (size_t)(m0 + wv * 32 + pr) * DI + kbase + pk;
  const u16* gA1 = gA0 + (size_t)16 * DI;
  const u16* gB0 = B + (size_t)br0 * DI + kbase + pk;
  const u16* gB1 = B + (size_t)br1 * DI + kbase + pk;

  f32x4 acc[4][4];
#pragma unroll
  for (int i = 0; i < 4; ++i)
#pragma unroll
    for (int j = 0; j < 4; ++j)
#pragma unroll
      for (int t = 0; t < 4; ++t) acc[i][j][t] = 0.f;

  g2l16(gA0, lA0[0]); g2l16(gA1, lA1[0]);
  g2l16(gB0, lB0[0]); g2l16(gB1, lB1[0]);

  for (int kt = 0; kt < 8; ++kt) {
    const int cur = kt & 1;
    __syncthreads();
    bf16x8 af[4], bfr[4];
#pragma unroll
    for (int i = 0; i < 4; ++i)
      af[i] = *reinterpret_cast<const bf16x8*>(&sA[cur][(wm + i * 16 + r) * 32 + q * 8]);
#pragma unroll
    for (int j = 0; j < 4; ++j)
      bfr[j] = *reinterpret_cast<const bf16x8*>(&sB[cur][(wn + j * 16 + r) * 32 + q * 8]);
    if (kt + 1 < 8) {
      gA0 += 32; gA1 += 32; gB0 += 32; gB1 += 32;
      g2l16(gA0, lA0[cur ^ 1]); g2l16(gA1, lA1[cur ^ 1]);
      g2l16(gB0, lB0[cur ^ 1]); g2l16(gB1, lB1[cur ^ 1]);
    }
#pragma unroll
    for (int i = 0; i < 4; ++i)
#pragma unroll
      for (int j = 0; j < 4; ++j)
        acc[i][j] = __builtin_amdgcn_mfma_f32_16x16x32_bf16(af[i], bfr[j], acc[i][j], 0, 0, 0);
  }

#pragma unroll
  for (int i = 0; i < 4; ++i)
#pragma unroll
    for (int j = 0; j < 4; ++j)
#pragma unroll
      for (int t = 0; t < 4; ++t) {
        const int row = m0 + wm + i * 16 + q * 4 + t;
        const int col = wn + j * 16 + r;
        if (col < NXP)
          part[((size_t)kz * NTOK + row) * NXP + col] = acc[i][j][t];
      }
}

// Reduce partials: cols 0..63 -> dtraw bf16 [NTOK,64]; 64..67 -> bc f32 [NTOK,4]
__global__ __launch_bounds__(256)
void xreduce_kernel(const float* __restrict__ part, u16* __restrict__ dtraw,
                    float* __restrict__ bc)
{
  const int i = blockIdx.x * 256 + threadIdx.x;
  if (i >= NTOK * NXP) return;
  const int row = i / NXP, col = i - row * NXP;
  float s = 0.f;
#pragma unroll
  for (int z = 0; z < 8; ++z) s += part[(size_t)z * NTOK * NXP + i];
  if (col < DTR) dtraw[(size_t)row * DTR + col] = f2bf(s);
  else           bc[row * 4 + (col - DTR)] = s;
}

// ---------------------------------------------------------------------------
// Depthwise causal conv (k=4, transposed weights) + bias + SiLU, x8 vectorized.
// One block per token; thread handles 8 consecutive channels.
// ---------------------------------------------------------------------------
__global__ __launch_bounds__(256)
void conv_silu_kernel(const u16* __restrict__ xp, const u16* __restrict__ cwT,
                      const u16* __restrict__ cb, u16* __restrict__ u)
{
  const int token = blockIdx.x;
  const int t = token & (SEQ - 1);
  const int d0 = threadIdx.x * 8;
  const ptrdiff_t base = (ptrdiff_t)token * DI + d0;
  float acc[8];
  u16x8 cbv = *(const u16x8*)(cb + d0);
#pragma unroll
  for (int k = 0; k < 8; ++k) acc[k] = bf2f(cbv[k]);
#pragma unroll
  for (int j = 0; j < 4; ++j) {
    if (t - 3 + j >= 0) {
      u16x8 xv = *(const u16x8*)(xp + base + (ptrdiff_t)(j - 3) * DI);
      u16x8 wv = *(const u16x8*)(cwT + j * DI + d0);
#pragma unroll
      for (int k = 0; k < 8; ++k) acc[k] += bf2f(wv[k]) * bf2f(xv[k]);
    }
  }
  u16x8 o;
#pragma unroll
  for (int k = 0; k < 8; ++k) {
    const float sg = 1.f / (1.f + __expf(-acc[k]));
    o[k] = f2bf(acc[k] * sg);
  }
  *(u16x8*)(u + base) = o;
}

// ---------------------------------------------------------------------------
// Chunked SSM scan (N=2 states), 4 channels per thread, CHUNK=32.
// ---------------------------------------------------------------------------
__global__ __launch_bounds__(256)
void scan_pass1(const u16* __restrict__ dtb, const u16* __restrict__ ub,
                const float* __restrict__ bc, const u16* __restrict__ a_log,
                float* __restrict__ S, float* __restrict__ hf0, float* __restrict__ hf1)
{
  const int g4 = blockIdx.x * 256 + threadIdx.x;   // NCHK*NCH/4
  const int chg = g4 & (NCH / 4 - 1);
  const int c = g4 >> 10;
  const int ch0 = chg * 4;
  const int b = ch0 >> 11;
  const int d0 = ch0 & (DI - 1);
  u16x8 av = *(const u16x8*)(a_log + d0 * 2);
  float A0[4], A1[4];
#pragma unroll
  for (int k = 0; k < 4; ++k) {
    A0[k] = -__expf(bf2f(av[2 * k]));
    A1[k] = -__expf(bf2f(av[2 * k + 1]));
  }
  float h0[4] = {0.f, 0.f, 0.f, 0.f}, h1[4] = {0.f, 0.f, 0.f, 0.f};
  float s[4] = {0.f, 0.f, 0.f, 0.f};
  const int row0 = b * SEQ + c * CHUNK;
  for (int i = 0; i < CHUNK; ++i) {
    const size_t row = row0 + i;
    u16x4 dtv = *(const u16x4*)(dtb + row * DI + d0);
    u16x4 uv  = *(const u16x4*)(ub + row * DI + d0);
    f32x2 Bv = *(const f32x2*)(bc + row * 4);
#pragma unroll
    for (int k = 0; k < 4; ++k) {
      const float dt = bf2f(dtv[k]);
      const float dtu = dt * bf2f(uv[k]);
      h0[k] = __expf(A0[k] * dt) * h0[k] + dtu * Bv[0];
      h1[k] = __expf(A1[k] * dt) * h1[k] + dtu * Bv[1];
      s[k] += dt;
    }
  }
  const size_t g0 = (size_t)c * NCH + ch0;
  *(f32x4*)(S + g0)   = f32x4{s[0], s[1], s[2], s[3]};
  *(f32x4*)(hf0 + g0) = f32x4{h0[0], h0[1], h0[2], h0[3]};
  *(f32x4*)(hf1 + g0) = f32x4{h1[0], h1[1], h1[2], h1[3]};
}

__global__ __launch_bounds__(256)
void scan_pass2(const float* __restrict__ S, const float* __restrict__ hf0,
                const float* __restrict__ hf1, const u16* __restrict__ a_log,
                float* __restrict__ hi0, float* __restrict__ hi1)
{
  const int ch = blockIdx.x * 256 + threadIdx.x;  // NCH
  const int d = ch & (DI - 1);
  const float A0 = -__expf(bf2f(a_log[d * 2 + 0]));
  const float A1 = -__expf(bf2f(a_log[d * 2 + 1]));
  float h0 = 0.f, h1 = 0.f;
  for (int c = 0; c < NCHK; ++c) {
    const size_t g = (size_t)c * NCH + ch;
    hi0[g] = h0; hi1[g] = h1;
    const float s = S[g];
    h0 = __expf(A0 * s) * h0 + hf0[g];
    h1 = __expf(A1 * s) * h1 + hf1[g];
  }
}

__global__ __launch_bounds__(256)
void scan_pass3(const u16* __restrict__ dtb, const u16* __restrict__ ub,
                const float* __restrict__ bc, const u16* __restrict__ zbuf,
                const u16* __restrict__ a_log, const u16* __restrict__ d_skip,
                const float* __restrict__ hi0, const float* __restrict__ hi1,
                u16* __restrict__ yb)
{
  const int g4 = blockIdx.x * 256 + threadIdx.x;
  const int chg = g4 & (NCH / 4 - 1);
  const int c = g4 >> 10;
  const int ch0 = chg * 4;
  const int b = ch0 >> 11;
  const int d0 = ch0 & (DI - 1);
  u16x8 av = *(const u16x8*)(a_log + d0 * 2);
  u16x4 dkv = *(const u16x4*)(d_skip + d0);
  float A0[4], A1[4], dsk[4];
#pragma unroll
  for (int k = 0; k < 4; ++k) {
    A0[k] = -__expf(bf2f(av[2 * k]));
    A1[k] = -__expf(bf2f(av[2 * k + 1]));
    dsk[k] = bf2f(dkv[k]);
  }
  const size_t g0 = (size_t)c * NCH + ch0;
  f32x4 h0v = *(const f32x4*)(hi0 + g0);
  f32x4 h1v = *(const f32x4*)(hi1 + g0);
  float h0[4], h1[4];
#pragma unroll
  for (int k = 0; k < 4; ++k) { h0[k] = h0v[k]; h1[k] = h1v[k]; }
  const int row0 = b * SEQ + c * CHUNK;
  for (int i = 0; i < CHUNK; ++i) {
    const size_t row = row0 + i;
    u16x4 dtv = *(const u16x4*)(dtb + row * DI + d0);
    u16x4 uv  = *(const u16x4*)(ub + row * DI + d0);
    u16x4 zv  = *(const u16x4*)(zbuf + row * DI + d0);
    f32x4 bcv = *(const f32x4*)(bc + row * 4);
    u16x4 o;
#pragma unroll
    for (int k = 0; k < 4; ++k) {
      const float dt = bf2f(dtv[k]);
      const float uu = bf2f(uv[k]);
      const float dtu = dt * uu;
      h0[k] = __expf(A0[k] * dt) * h0[k] + dtu * bcv[0];
      h1[k] = __expf(A1[k] * dt) * h1[k] + dtu * bcv[1];
      const float y = h0[k] * bcv[2] + h1[k] * bcv[3];
      const float z = bf2f(zv[k]);
      const float sz = z / (1.f + __expf(-z));
      o[k] = f2bf((y + dsk[k] * uu) * sz);
    }
    *(u16x4*)(yb + row * DI + d0) = o;    // in-place over dtb: ok
  }
}

// ---------------------------------------------------------------------------
extern "C" void kernel_launch(void* const* d_in, const int* in_sizes, int n_in,
                              void* d_out, int out_size, void* d_ws, size_t ws_size,
                              hipStream_t stream)
{
  const void* x       = d_in[0];
  const void* w_in    = d_in[1];
  const void* conv_w  = d_in[2];
  const void* conv_b  = d_in[3];
  const void* w_xproj = d_in[4];
  const void* w_dt    = d_in[5];
  const void* b_dt    = d_in[6];
  const void* a_log   = d_in[7];
  const void* d_skip  = d_in[8];
  const void* w_out   = d_in[9];
  const void* ln1_g   = d_in[10];
  const void* ln1_b   = d_in[11];
  const void* ln2_g   = d_in[12];
  const void* ln2_b   = d_in[13];
  const void* ffn_w1  = d_in[14];
  const void* ffn_b1  = d_in[15];
  const void* ffn_w2  = d_in[16];
  const void* ffn_b2  = d_in[17];
  char* ws = (char*)d_ws;

  // ---- workspace layout (high-water ~127 MB) ----
  const size_t o_flag  = 0;
  const size_t o_small = 256;
  const size_t o_cwout = o_small + 65536;
  const size_t o_cff1  = o_cwout + (size_t)DM * DI * 2;
  const size_t o_cff2  = o_cff1  + (size_t)DM * DM * 2;
  const size_t o_cxp   = o_cff2  + (size_t)DM * DM * 2;
  const size_t o_cwdt  = o_cxp   + (size_t)NXP * DI * 2;
  const size_t o_xn    = 9437184;                         // 16 MiB region
  const size_t o_xp    = o_xn + (size_t)NTOK * DM * 2;    // 32 MiB
  const size_t o_z     = o_xp + (size_t)NTOK * DI * 2;    // 32 MiB
  const size_t o_u     = o_z  + (size_t)NTOK * DI * 2;    // 32 MiB
  const size_t o_bc    = o_u  + (size_t)NTOK * DI * 2;    // 128 KiB
  // scan state overlays the xn region (dead during the scan):
  const size_t SCN = (size_t)NCHK * NCH * 4;              // 2 MiB each
  const size_t o_S   = o_xn + 0 * SCN;
  const size_t o_hf0 = o_xn + 1 * SCN;
  const size_t o_hf1 = o_xn + 2 * SCN;
  const size_t o_hi0 = o_xn + 3 * SCN;
  const size_t o_hi1 = o_xn + 4 * SCN;                    // ends +10 MiB < 16 MiB

  int*   flagp   = (int*)(ws + o_flag);
  u16*   csmall  = (u16*)(ws + o_small);
  u16*   c_cwT   = csmall +     0;       // transposed conv weights [4][DI]
  u16*   c_convb = csmall +  8192;
  u16*   c_bdt   = csmall + 10240;
  u16*   c_alog  = csmall + 12288;
  u16*   c_dskip = csmall + 16384;
  u16*   c_ln1g  = csmall + 18432;
  u16*   c_ln1b  = csmall + 19456;
  u16*   c_ln2g  = csmall + 20480;
  u16*   c_ln2b  = csmall + 21504;
  u16*   c_fb1   = csmall + 22528;
  u16*   c_fb2   = csmall + 23552;
  u16*   c_wout  = (u16*)(ws + o_cwout);
  u16*   c_ff1   = (u16*)(ws + o_cff1);
  u16*   c_ff2   = (u16*)(ws + o_cff2);
  u16*   c_xproj = (u16*)(ws + o_cxp);
  u16*   c_wdt   = (u16*)(ws + o_cwdt);
  u16*   c_win   = (u16*)(ws + o_u);     // overlays u (dead until conv)
  u16*   xn      = (u16*)(ws + o_xn);
  u16*   xp      = (u16*)(ws + o_xp);
  u16*   zb      = (u16*)(ws + o_z);
  u16*   u       = (u16*)(ws + o_u);
  float* part    = (float*)(ws + o_xp);  // overlays xp (dead after conv)
  u16*   dtraw   = (u16*)(ws + o_xn);    // overlays xn (dead after in_proj)
  u16*   dtb     = xp;                   // overlays part (dead after reduce)
  u16*   yb      = xp;
  float* bc      = (float*)(ws + o_bc);
  float* S       = (float*)(ws + o_S);   // scan arrays overlay xn region;
  float* hf0     = (float*)(ws + o_hf0); // dtraw (first 1 MB) is consumed by
  float* hf1     = (float*)(ws + o_hf1); // the dt-GEMM before pass1 writes S
  float* hi0     = (float*)(ws + o_hi0);
  float* hi1     = (float*)(ws + o_hi1);
  float* h       = (float*)(ws + o_z);   // overlays z (dead after pass3)
  u16*   hn      = (u16*)(ws + o_xn);    // overlays scan arrays (dead)
  u16*   f1      = (u16*)(ws + o_u);     // overlays u (dead)

  const dim3 blk(256);

  // 0) detect dtype; weight copies are no-ops when inputs are already bf16
  detect_kernel<<<1, blk, 0, stream>>>((const u16*)x, flagp);
  convert_kernel<<<(2 * DI * DM) / 256, blk, 0, stream>>>(w_in, c_win, 2 * DI * DM, flagp);
  convert_kernel<<<(NXP * DI + 255) / 256, blk, 0, stream>>>(w_xproj, c_xproj, NXP * DI, flagp);
  convert_kernel<<<(DI * DTR) / 256, blk, 0, stream>>>(w_dt, c_wdt, DI * DTR, flagp);
  convert_kernel<<<(DM * DI) / 256, blk, 0, stream>>>(w_out, c_wout, DM * DI, flagp);
  convert_kernel<<<(DM * DM) / 256, blk, 0, stream>>>(ffn_w1, c_ff1, DM * DM, flagp);
  convert_kernel<<<(DM * DM) / 256, blk, 0, stream>>>(ffn_w2, c_ff2, DM * DM, flagp);
  convert_small_kernel<<<96, blk, 0, stream>>>(conv_w, conv_b, b_dt, a_log, d_skip,
                                               ln1_g, ln1_b, ln2_g, ln2_b, ffn_b1, ffn_b2,
                                               csmall, flagp);

  // 1) LN1(x) -> xn
  ln_kernel<true><<<NTOK / 2, blk, 0, stream>>>(x, c_ln1g, c_ln1b, xn, flagp);
  // 2) fused in_proj: [xp | z] = xn @ w_in^T   (N=4096 -> LNBX=5, 2048 blocks)
  gemm_kernel<6, 5><<<2048, blk, 0, stream>>>(xn, c_win, (const u16*)w_in,
                                              NTOK, 2 * DI, DM,
                                              nullptr, nullptr, nullptr, flagp, xp, zb);
  // 3) u = silu(conv(xp) + conv_b)   (vectorized x8; one block per token)
  conv_silu_kernel<<<NTOK, blk, 0, stream>>>(xp, c_cwT, c_convb, u);
  // 4) x_proj split-K (partials) + reduce -> dtraw (bf16), bc (f32)
  xproj_splitk<<<dim3(8, 64), blk, 0, stream>>>(u, c_xproj, (const u16*)w_xproj,
                                                flagp, part);
  xreduce_kernel<<<(NTOK * NXP + 255) / 256, blk, 0, stream>>>(part, dtraw, bc);
  // 5) dt = softplus(dtraw @ w_dt^T + b_dt)   (N=2048 -> LNBX=4)
  gemm_kernel<2, 4><<<1024, blk, 0, stream>>>(dtraw, c_wdt, (const u16*)w_dt,
                                              NTOK, DI, DTR,
                                              c_bdt, nullptr, nullptr, flagp, dtb, nullptr);
  // 6) chunked scan -> yb = (y + d_skip*u) * silu(z)
  scan_pass1<<<NCHK * NCH / 4 / 256, blk, 0, stream>>>(dtb, u, bc, c_alog, S, hf0, hf1);
  scan_pass2<<<NCH / 256, blk, 0, stream>>>(S, hf0, hf1, c_alog, hi0, hi1);
  scan_pass3<<<NCHK * NCH / 4 / 256, blk, 0, stream>>>(dtb, u, bc, zb, c_alog, c_dskip,
                                                       hi0, hi1, yb);
  // 7) h = x + yb @ w_out^T   (N=1024 -> LNBX=3)
  gemm_kernel<3, 3><<<512, blk, 0, stream>>>(yb, c_wout, (const u16*)w_out,
                                             NTOK, DM, DI,
                                             nullptr, (const u16*)x, (const float*)x,
                                             flagp, h, nullptr);
  // 8) LN2(h) -> hn
  ln_kernel<false><<<NTOK / 2, blk, 0, stream>>>(h, c_ln2g, c_ln2b, hn, flagp);
  // 9) f1 = relu(hn @ ffn_w1^T + b1)
  gemm_kernel<4, 3><<<512, blk, 0, stream>>>(hn, c_ff1, (const u16*)ffn_w1,
                                             NTOK, DM, DM,
                                             c_fb1, nullptr, nullptr, flagp, f1, nullptr);
  // 10) out = h + f1 @ ffn_w2^T + b2
  gemm_kernel<5, 3><<<512, blk, 0, stream>>>(f1, c_ff2, (const u16*)ffn_w2,
                                             NTOK, DM, DM,
                                             c_fb2, nullptr, h, flagp, d_out, nullptr);
}

// Round 6
// 480.708 us; speedup vs baseline: 1.3776x; 1.0481x over previous
//
#include <hip/hip_runtime.h>

typedef unsigned short u16;
typedef __bf16 bf16x8 __attribute__((ext_vector_type(8)));
typedef float f32x4 __attribute__((ext_vector_type(4)));
typedef float f32x2 __attribute__((ext_vector_type(2)));
typedef u16 u16x4 __attribute__((ext_vector_type(4)));
typedef u16 u16x8 __attribute__((ext_vector_type(8)));

// Problem constants
#define SEQ   4096
#define DM    1024
#define DI    2048
#define NTOK  8192      // BATCH * SEQ
#define NXP   68        // DT_RANK + 2*D_STATE
#define DTR   64        // DT_RANK
#define NCH   4096      // BATCH * DI channels for scan
#define CHUNK 32
#define NCHK  128       // SEQ / CHUNK

__device__ __forceinline__ float bf2f(u16 v) {
  union { unsigned u; float f; } x; x.u = ((unsigned)v) << 16; return x.f;
}
__device__ __forceinline__ u16 f2bf(float f) {
  unsigned u = __float_as_uint(f);
  return (u16)((u + 0x7FFFu + ((u >> 16) & 1u)) >> 16);   // RNE
}

// async global->LDS DMA, 16B/lane; LDS dest = wave-uniform base + lane*16
__device__ __forceinline__ void g2l16(const u16* g, u16* l) {
  __builtin_amdgcn_global_load_lds(
      (const __attribute__((address_space(1))) unsigned int*)g,
      (__attribute__((address_space(3))) unsigned int*)l, 16, 0, 0);
}

// ---------------------------------------------------------------------------
// Input dtype detection (f32 inputs -> low u16 has huge bf16 exponents)
// ---------------------------------------------------------------------------
__global__ __launch_bounds__(256)
void detect_kernel(const u16* __restrict__ x, int* __restrict__ flag)
{
  __shared__ int tot;
  if (threadIdx.x == 0) tot = 0;
  __syncthreads();
  int cnt = 0;
  for (int i = threadIdx.x; i < 4096; i += 256) {
    const int e = (x[2 * i] >> 7) & 0xFF;
    if (e > 167) cnt++;
  }
  atomicAdd(&tot, cnt);
  __syncthreads();
  if (threadIdx.x == 0) flag[0] = (tot >= 8) ? 1 : 0;
}

// All 6 big weights in ONE launch, 8 elems/thread; NO-OP when inputs are bf16.
#define NW0 4194304   // w_in
#define NW1  139264   // w_xproj
#define NW2  131072   // w_dt
#define NW3 2097152   // w_out
#define NW4 1048576   // ffn_w1
#define NW5 1048576   // ffn_w2
__global__ __launch_bounds__(256)
void convert_big(const float* __restrict__ s0, const float* __restrict__ s1,
                 const float* __restrict__ s2, const float* __restrict__ s3,
                 const float* __restrict__ s4, const float* __restrict__ s5,
                 u16* __restrict__ d0, u16* __restrict__ d1, u16* __restrict__ d2,
                 u16* __restrict__ d3, u16* __restrict__ d4, u16* __restrict__ d5,
                 const int* __restrict__ flag)
{
  if (*flag == 0) return;
  long e = ((long)blockIdx.x * 256 + threadIdx.x) * 8;
  const long c1 = NW0, c2 = c1 + NW1, c3 = c2 + NW2, c4 = c3 + NW3,
             c5 = c4 + NW4, c6 = c5 + NW5;
  if (e >= c6) return;
  const float* s; u16* d;
  if      (e < c1) { s = s0;          d = d0; }
  else if (e < c2) { s = s1; e -= c1; d = d1; }
  else if (e < c3) { s = s2; e -= c2; d = d2; }
  else if (e < c4) { s = s3; e -= c3; d = d3; }
  else if (e < c5) { s = s4; e -= c4; d = d4; }
  else             { s = s5; e -= c5; d = d5; }
  f32x4 a = *(const f32x4*)(s + e);
  f32x4 b = *(const f32x4*)(s + e + 4);
  u16x8 o;
#pragma unroll
  for (int k = 0; k < 4; ++k) { o[k] = f2bf(a[k]); o[4 + k] = f2bf(b[k]); }
  *(u16x8*)(d + e) = o;
}

// All 11 small vectors in one launch; conv_w stored TRANSPOSED [4][DI].
__global__ __launch_bounds__(256)
void convert_small_kernel(const void* s0, const void* s1, const void* s2,
                          const void* s3, const void* s4, const void* s5,
                          const void* s6, const void* s7, const void* s8,
                          const void* s9, const void* s10,
                          u16* __restrict__ dst, const int* __restrict__ flag)
{
  const int i = blockIdx.x * 256 + threadIdx.x;
  if (i >= 24576) return;
  const void* src; int off; int dsti = i;
  if      (i < 8192)  { src = s0;  off = i;
                        dsti = (off & 3) * DI + (off >> 2); }  // conv_w -> [j][d]
  else if (i < 10240) { src = s1;  off = i - 8192; }   // conv_b
  else if (i < 12288) { src = s2;  off = i - 10240; }  // b_dt
  else if (i < 16384) { src = s3;  off = i - 12288; }  // a_log
  else if (i < 18432) { src = s4;  off = i - 16384; }  // d_skip
  else if (i < 19456) { src = s5;  off = i - 18432; }  // ln1_g
  else if (i < 20480) { src = s6;  off = i - 19456; }  // ln1_b
  else if (i < 21504) { src = s7;  off = i - 20480; }  // ln2_g
  else if (i < 22528) { src = s8;  off = i - 21504; }  // ln2_b
  else if (i < 23552) { src = s9;  off = i - 22528; }  // ffn_b1
  else                { src = s10; off = i - 23552; }  // ffn_b2
  dst[dsti] = (*flag) ? f2bf(((const float*)src)[off]) : ((const u16*)src)[off];
}

// ---------------------------------------------------------------------------
// LayerNorm: 2 rows per block, 8 elems per thread, vectorized loads/stores.
// ---------------------------------------------------------------------------
template<bool DUAL>
__global__ __launch_bounds__(256)
void ln_kernel(const void* __restrict__ xin, const u16* __restrict__ gw,
               const u16* __restrict__ bw, u16* __restrict__ outp,
               const int* __restrict__ flag)
{
  const int tid = threadIdx.x;
  const int sub = tid >> 7;                  // row within block
  const int col0 = (tid & 127) * 8;
  const int row = blockIdx.x * 2 + sub;
  const bool isf32 = DUAL ? (*flag != 0) : true;
  float v[8];
  if (isf32) {
    const float* xf = (const float*)xin + (size_t)row * DM + col0;
    f32x4 a = *(const f32x4*)xf, b2 = *(const f32x4*)(xf + 4);
#pragma unroll
    for (int k = 0; k < 4; ++k) { v[k] = a[k]; v[4 + k] = b2[k]; }
  } else {
    u16x8 xb = *(const u16x8*)((const u16*)xin + (size_t)row * DM + col0);
#pragma unroll
    for (int k = 0; k < 8; ++k) v[k] = bf2f(xb[k]);
  }
  float s = 0.f, s2 = 0.f;
#pragma unroll
  for (int k = 0; k < 8; ++k) { s += v[k]; s2 += v[k] * v[k]; }
#pragma unroll
  for (int off = 32; off > 0; off >>= 1) {
    s  += __shfl_down(s,  off);
    s2 += __shfl_down(s2, off);
  }
  __shared__ float red[4], red2[4];
  __shared__ f32x2 stat[2];
  const int wv = tid >> 6;
  if ((tid & 63) == 0) { red[wv] = s; red2[wv] = s2; }
  __syncthreads();
  if ((tid & 127) == 0) {
    float ts = red[sub * 2] + red[sub * 2 + 1];
    float t2 = red2[sub * 2] + red2[sub * 2 + 1];
    float mu = ts * (1.f / DM);
    float var = t2 * (1.f / DM) - mu * mu;
    stat[sub] = f32x2{mu, rsqrtf(var + 1e-5f)};
  }
  __syncthreads();
  const float mu = stat[sub][0], rs = stat[sub][1];
  u16x8 gv = *(const u16x8*)(gw + col0), bv = *(const u16x8*)(bw + col0);
  u16x8 o;
#pragma unroll
  for (int k = 0; k < 8; ++k)
    o[k] = f2bf((v[k] - mu) * rs * bf2f(gv[k]) + bf2f(bv[k]));
  *(u16x8*)(outp + (size_t)row * DM + col0) = o;
}

// ---------------------------------------------------------------------------
// bf16 MFMA GEMM: C[M,N] = A[M,K] @ B[N,K]^T.  128x128 tile, BK=32,
// double-buffered LDS, global_load_lds(16B) prefetch, one barrier/iter,
// XCD swizzle, XOR bank-swizzle on LDS chunk placement:
//   slot(row, s) holds global k-chunk s ^ ((row>>1)&3)  -> frag ds_read_b128
//   lands 2 lanes/bank-group (free) instead of 8-way conflicts.
// Requires: M%128==0, N%128==0, K%32==0, gridDim.x == (N/128)*64, N/128==1<<LNBX.
// EPI: 1 bf16 | 2 +bias,softplus->bf16 | 3 +x(flag dtype)->f32 |
//      4 +bias,relu->bf16 | 5 +bias+addf32 -> out(bf16/f32 per flag) |
//      6 split store: col<DI -> Cp (bf16), else -> Cp2 (bf16), row stride DI
// ---------------------------------------------------------------------------
template<int EPI, int LNBX>
__global__ __launch_bounds__(256, 2)
void gemm_kernel(const u16* __restrict__ A, const u16* __restrict__ Bc,
                 const u16* __restrict__ Braw,
                 int M, int N, int K,
                 const u16* __restrict__ bias, const u16* __restrict__ addbf,
                 const float* __restrict__ addf, const int* __restrict__ dtflag,
                 void* __restrict__ Cp, void* __restrict__ Cp2)
{
  __shared__ __align__(16) u16 sA[2][128 * 32];
  __shared__ __align__(16) u16 sB[2][128 * 32];
  const int fl = *dtflag;
  const u16* __restrict__ B = fl ? Bc : Braw;
  const int tid = threadIdx.x;
  const int b = blockIdx.x;
  const int xcd = b & 7;
  const int kk = b >> 3;
  const int bx = kk & ((1 << LNBX) - 1);
  const int by = xcd * 8 + (kk >> LNBX);
  const int m0 = by * 128;
  const int n0 = bx * 128;
  const int lane = tid & 63;
  const int wv = tid >> 6;
  const int wm = (wv & 1) * 64;
  const int wn = (wv >> 1) * 64;
  const int r = lane & 15;
  const int q = lane >> 4;
  const int rsw = (r >> 1) & 3;        // read-side bank swizzle

  const int pr = lane >> 2;            // 0..15 row in 16-row staging chunk
  const int kc = (lane & 3) ^ ((pr >> 1) & 3);   // swizzled source k-chunk
  const int pk = kc * 8;
  u16* lA0[2] = { &sA[0][(wv * 2 + 0) * 512], &sA[1][(wv * 2 + 0) * 512] };
  u16* lA1[2] = { &sA[0][(wv * 2 + 1) * 512], &sA[1][(wv * 2 + 1) * 512] };
  u16* lB0[2] = { &sB[0][(wv * 2 + 0) * 512], &sB[1][(wv * 2 + 0) * 512] };
  u16* lB1[2] = { &sB[0][(wv * 2 + 1) * 512], &sB[1][(wv * 2 + 1) * 512] };
  const u16* gA0 = A + (size_t)(m0 + wv * 32 + pr) * K + pk;
  const u16* gA1 = gA0 + (size_t)16 * K;
  const u16* gB0 = B + (size_t)(n0 + wv * 32 + pr) * K + pk;
  const u16* gB1 = gB0 + (size_t)16 * K;

  f32x4 acc[4][4];
#pragma unroll
  for (int i = 0; i < 4; ++i)
#pragma unroll
    for (int j = 0; j < 4; ++j)
#pragma unroll
      for (int t = 0; t < 4; ++t) acc[i][j][t] = 0.f;

  g2l16(gA0, lA0[0]); g2l16(gA1, lA1[0]);
  g2l16(gB0, lB0[0]); g2l16(gB1, lB1[0]);

  const int nk = K >> 5;
  for (int kt = 0; kt < nk; ++kt) {
    const int cur = kt & 1;
    __syncthreads();   // drains vmcnt(0): tile-kt deposits complete
    bf16x8 af[4], bfr[4];
#pragma unroll
    for (int i = 0; i < 4; ++i)
      af[i] = *reinterpret_cast<const bf16x8*>(
          &sA[cur][(wm + i * 16 + r) * 32 + (q ^ rsw) * 8]);
#pragma unroll
    for (int j = 0; j < 4; ++j)
      bfr[j] = *reinterpret_cast<const bf16x8*>(
          &sB[cur][(wn + j * 16 + r) * 32 + (q ^ rsw) * 8]);
    if (kt + 1 < nk) {
      gA0 += 32; gA1 += 32; gB0 += 32; gB1 += 32;
      g2l16(gA0, lA0[cur ^ 1]); g2l16(gA1, lA1[cur ^ 1]);
      g2l16(gB0, lB0[cur ^ 1]); g2l16(gB1, lB1[cur ^ 1]);
    }
#pragma unroll
    for (int i = 0; i < 4; ++i)
#pragma unroll
      for (int j = 0; j < 4; ++j)
        acc[i][j] = __builtin_amdgcn_mfma_f32_16x16x32_bf16(af[i], bfr[j], acc[i][j], 0, 0, 0);
  }

  // epilogue: D row = wm+i*16+q*4+t (M), col = wn+j*16+r (N)
#pragma unroll
  for (int i = 0; i < 4; ++i) {
#pragma unroll
    for (int j = 0; j < 4; ++j) {
#pragma unroll
      for (int t = 0; t < 4; ++t) {
        const int row = m0 + wm + i * 16 + q * 4 + t;
        const int col = n0 + wn + j * 16 + r;
        float v = acc[i][j][t];
        if (EPI == 6) {
          const size_t rb = (size_t)row * DI;
          if (col < DI) ((u16*)Cp)[rb + col] = f2bf(v);
          else          ((u16*)Cp2)[rb + col - DI] = f2bf(v);
        } else {
          const size_t idx = (size_t)row * N + col;
          if (EPI == 1) {
            ((u16*)Cp)[idx] = f2bf(v);
          } else if (EPI == 2) {           // dt = softplus(v + b_dt)
            v += bf2f(bias[col]);
            v = (v > 15.f) ? v : __logf(1.f + __expf(v));
            ((u16*)Cp)[idx] = f2bf(v);
          } else if (EPI == 3) {           // h = x + mamba_out (f32)
            v += fl ? addf[idx] : bf2f(addbf[idx]);
            ((float*)Cp)[idx] = v;
          } else if (EPI == 4) {           // relu(v + b1)
            v += bf2f(bias[col]);
            ((u16*)Cp)[idx] = f2bf(fmaxf(v, 0.f));
          } else {                         // out = h + v + b2
            v += bf2f(bias[col]) + addf[idx];
            if (fl) ((float*)Cp)[idx] = v;
            else    ((u16*)Cp)[idx] = f2bf(v);
          }
        }
      }
    }
  }
}

// ---------------------------------------------------------------------------
// x_proj split-K: part[z] = u[:, z*256:(z+1)*256] @ w_xproj[:, same]^T
// grid (8, 64). Output f32 partials [8, NTOK, 68]. Same swizzles.
// ---------------------------------------------------------------------------
__global__ __launch_bounds__(256, 2)
void xproj_splitk(const u16* __restrict__ A, const u16* __restrict__ Bc,
                  const u16* __restrict__ Braw, const int* __restrict__ dtflag,
                  float* __restrict__ part)
{
  __shared__ __align__(16) u16 sA[2][128 * 32];
  __shared__ __align__(16) u16 sB[2][128 * 32];
  const int fl = *dtflag;
  const u16* __restrict__ B = fl ? Bc : Braw;
  const int tid = threadIdx.x;
  const int kz = blockIdx.x;           // 0..7
  const int m0 = blockIdx.y * 128;
  const int kbase = kz * 256;
  const int lane = tid & 63;
  const int wv = tid >> 6;
  const int wm = (wv & 1) * 64;
  const int wn = (wv >> 1) * 64;
  const int r = lane & 15;
  const int q = lane >> 4;
  const int rsw = (r >> 1) & 3;
  const int pr = lane >> 2;
  const int kc = (lane & 3) ^ ((pr >> 1) & 3);
  const int pk = kc * 8;

  u16* lA0[2] = { &sA[0][(wv * 2 + 0) * 512], &sA[1][(wv * 2 + 0) * 512] };
  u16* lA1[2] = { &sA[0][(wv * 2 + 1) * 512], &sA[1][(wv * 2 + 1) * 512] };
  u16* lB0[2] = { &sB[0][(wv * 2 + 0) * 512], &sB[1][(wv * 2 + 0) * 512] };
  u16* lB1[2] = { &sB[0][(wv * 2 + 1) * 512], &sB[1][(wv * 2 + 1) * 512] };
  int br0 = wv * 32 + pr;      if (br0 > 67) br0 = 67;   // junk cols unused
  int br1 = wv * 32 + 16 + pr; if (br1 > 67) br1 = 67;
  const u16* gA0 = A + (size_t)(m0 + wv * 32 + pr) * DI + kbase + pk;
  const u16* gA1 = gA0 + (size_t)16 * DI;
  const u16* gB0 = B + (size_t)br0 * DI + kbase + pk;
  const u16* gB1 = B + (size_t)br1 * DI + kbase + pk;

  f32x4 acc[4][4];
#pragma unroll
  for (int i = 0; i < 4; ++i)
#pragma unroll
    for (int j = 0; j < 4; ++j)
#pragma unroll
      for (int t = 0; t < 4; ++t) acc[i][j][t] = 0.f;

  g2l16(gA0, lA0[0]); g2l16(gA1, lA1[0]);
  g2l16(gB0, lB0[0]); g2l16(gB1, lB1[0]);

  for (int kt = 0; kt < 8; ++kt) {
    const int cur = kt & 1;
    __syncthreads();
    bf16x8 af[4], bfr[4];
#pragma unroll
    for (int i = 0; i < 4; ++i)
      af[i] = *reinterpret_cast<const bf16x8*>(
          &sA[cur][(wm + i * 16 + r) * 32 + (q ^ rsw) * 8]);
#pragma unroll
    for (int j = 0; j < 4; ++j)
      bfr[j] = *reinterpret_cast<const bf16x8*>(
          &sB[cur][(wn + j * 16 + r) * 32 + (q ^ rsw) * 8]);
    if (kt + 1 < 8) {
      gA0 += 32; gA1 += 32; gB0 += 32; gB1 += 32;
      g2l16(gA0, lA0[cur ^ 1]); g2l16(gA1, lA1[cur ^ 1]);
      g2l16(gB0, lB0[cur ^ 1]); g2l16(gB1, lB1[cur ^ 1]);
    }
#pragma unroll
    for (int i = 0; i < 4; ++i)
#pragma unroll
      for (int j = 0; j < 4; ++j)
        acc[i][j] = __builtin_amdgcn_mfma_f32_16x16x32_bf16(af[i], bfr[j], acc[i][j], 0, 0, 0);
  }

#pragma unroll
  for (int i = 0; i < 4; ++i)
#pragma unroll
    for (int j = 0; j < 4; ++j)
#pragma unroll
      for (int t = 0; t < 4; ++t) {
        const int row = m0 + wm + i * 16 + q * 4 + t;
        const int col = wn + j * 16 + r;
        if (col < NXP)
          part[((size_t)kz * NTOK + row) * NXP + col] = acc[i][j][t];
      }
}

// Reduce partials: cols 0..63 -> dtraw bf16 [NTOK,64]; 64..67 -> bc f32 [NTOK,4]
__global__ __launch_bounds__(256)
void xreduce_kernel(const float* __restrict__ part, u16* __restrict__ dtraw,
                    float* __restrict__ bc)
{
  const int i = blockIdx.x * 256 + threadIdx.x;
  if (i >= NTOK * NXP) return;
  const int row = i / NXP, col = i - row * NXP;
  float s = 0.f;
#pragma unroll
  for (int z = 0; z < 8; ++z) s += part[(size_t)z * NTOK * NXP + i];
  if (col < DTR) dtraw[(size_t)row * DTR + col] = f2bf(s);
  else           bc[row * 4 + (col - DTR)] = s;
}

// ---------------------------------------------------------------------------
// Depthwise causal conv (k=4, transposed weights) + bias + SiLU, x8 vectorized.
// ---------------------------------------------------------------------------
__global__ __launch_bounds__(256)
void conv_silu_kernel(const u16* __restrict__ xp, const u16* __restrict__ cwT,
                      const u16* __restrict__ cb, u16* __restrict__ u)
{
  const int token = blockIdx.x;
  const int t = token & (SEQ - 1);
  const int d0 = threadIdx.x * 8;
  const ptrdiff_t base = (ptrdiff_t)token * DI + d0;
  float acc[8];
  u16x8 cbv = *(const u16x8*)(cb + d0);
#pragma unroll
  for (int k = 0; k < 8; ++k) acc[k] = bf2f(cbv[k]);
#pragma unroll
  for (int j = 0; j < 4; ++j) {
    if (t - 3 + j >= 0) {
      u16x8 xv = *(const u16x8*)(xp + base + (ptrdiff_t)(j - 3) * DI);
      u16x8 wv = *(const u16x8*)(cwT + j * DI + d0);
#pragma unroll
      for (int k = 0; k < 8; ++k) acc[k] += bf2f(wv[k]) * bf2f(xv[k]);
    }
  }
  u16x8 o;
#pragma unroll
  for (int k = 0; k < 8; ++k) {
    const float sg = 1.f / (1.f + __expf(-acc[k]));
    o[k] = f2bf(acc[k] * sg);
  }
  *(u16x8*)(u + base) = o;
}

// ---------------------------------------------------------------------------
// Chunked SSM scan (N=2 states), 4 channels per thread, CHUNK=32.
// ---------------------------------------------------------------------------
__global__ __launch_bounds__(256)
void scan_pass1(const u16* __restrict__ dtb, const u16* __restrict__ ub,
                const float* __restrict__ bc, const u16* __restrict__ a_log,
                float* __restrict__ S, float* __restrict__ hf0, float* __restrict__ hf1)
{
  const int g4 = blockIdx.x * 256 + threadIdx.x;   // NCHK*NCH/4
  const int chg = g4 & (NCH / 4 - 1);
  const int c = g4 >> 10;
  const int ch0 = chg * 4;
  const int b = ch0 >> 11;
  const int d0 = ch0 & (DI - 1);
  u16x8 av = *(const u16x8*)(a_log + d0 * 2);
  float A0[4], A1[4];
#pragma unroll
  for (int k = 0; k < 4; ++k) {
    A0[k] = -__expf(bf2f(av[2 * k]));
    A1[k] = -__expf(bf2f(av[2 * k + 1]));
  }
  float h0[4] = {0.f, 0.f, 0.f, 0.f}, h1[4] = {0.f, 0.f, 0.f, 0.f};
  float s[4] = {0.f, 0.f, 0.f, 0.f};
  const int row0 = b * SEQ + c * CHUNK;
  for (int i = 0; i < CHUNK; ++i) {
    const size_t row = row0 + i;
    u16x4 dtv = *(const u16x4*)(dtb + row * DI + d0);
    u16x4 uv  = *(const u16x4*)(ub + row * DI + d0);
    f32x2 Bv = *(const f32x2*)(bc + row * 4);
#pragma unroll
    for (int k = 0; k < 4; ++k) {
      const float dt = bf2f(dtv[k]);
      const float dtu = dt * bf2f(uv[k]);
      h0[k] = __expf(A0[k] * dt) * h0[k] + dtu * Bv[0];
      h1[k] = __expf(A1[k] * dt) * h1[k] + dtu * Bv[1];
      s[k] += dt;
    }
  }
  const size_t g0 = (size_t)c * NCH + ch0;
  *(f32x4*)(S + g0)   = f32x4{s[0], s[1], s[2], s[3]};
  *(f32x4*)(hf0 + g0) = f32x4{h0[0], h0[1], h0[2], h0[3]};
  *(f32x4*)(hf1 + g0) = f32x4{h1[0], h1[1], h1[2], h1[3]};
}

__global__ __launch_bounds__(256)
void scan_pass2(const float* __restrict__ S, const float* __restrict__ hf0,
                const float* __restrict__ hf1, const u16* __restrict__ a_log,
                float* __restrict__ hi0, float* __restrict__ hi1)
{
  const int ch = blockIdx.x * 256 + threadIdx.x;  // NCH
  const int d = ch & (DI - 1);
  const float A0 = -__expf(bf2f(a_log[d * 2 + 0]));
  const float A1 = -__expf(bf2f(a_log[d * 2 + 1]));
  float h0 = 0.f, h1 = 0.f;
  for (int c = 0; c < NCHK; ++c) {
    const size_t g = (size_t)c * NCH + ch;
    hi0[g] = h0; hi1[g] = h1;
    const float s = S[g];
    h0 = __expf(A0 * s) * h0 + hf0[g];
    h1 = __expf(A1 * s) * h1 + hf1[g];
  }
}

__global__ __launch_bounds__(256)
void scan_pass3(const u16* __restrict__ dtb, const u16* __restrict__ ub,
                const float* __restrict__ bc, const u16* __restrict__ zbuf,
                const u16* __restrict__ a_log, const u16* __restrict__ d_skip,
                const float* __restrict__ hi0, const float* __restrict__ hi1,
                u16* __restrict__ yb)
{
  const int g4 = blockIdx.x * 256 + threadIdx.x;
  const int chg = g4 & (NCH / 4 - 1);
  const int c = g4 >> 10;
  const int ch0 = chg * 4;
  const int b = ch0 >> 11;
  const int d0 = ch0 & (DI - 1);
  u16x8 av = *(const u16x8*)(a_log + d0 * 2);
  u16x4 dkv = *(const u16x4*)(d_skip + d0);
  float A0[4], A1[4], dsk[4];
#pragma unroll
  for (int k = 0; k < 4; ++k) {
    A0[k] = -__expf(bf2f(av[2 * k]));
    A1[k] = -__expf(bf2f(av[2 * k + 1]));
    dsk[k] = bf2f(dkv[k]);
  }
  const size_t g0 = (size_t)c * NCH + ch0;
  f32x4 h0v = *(const f32x4*)(hi0 + g0);
  f32x4 h1v = *(const f32x4*)(hi1 + g0);
  float h0[4], h1[4];
#pragma unroll
  for (int k = 0; k < 4; ++k) { h0[k] = h0v[k]; h1[k] = h1v[k]; }
  const int row0 = b * SEQ + c * CHUNK;
  for (int i = 0; i < CHUNK; ++i) {
    const size_t row = row0 + i;
    u16x4 dtv = *(const u16x4*)(dtb + row * DI + d0);
    u16x4 uv  = *(const u16x4*)(ub + row * DI + d0);
    u16x4 zv  = *(const u16x4*)(zbuf + row * DI + d0);
    f32x4 bcv = *(const f32x4*)(bc + row * 4);
    u16x4 o;
#pragma unroll
    for (int k = 0; k < 4; ++k) {
      const float dt = bf2f(dtv[k]);
      const float uu = bf2f(uv[k]);
      const float dtu = dt * uu;
      h0[k] = __expf(A0[k] * dt) * h0[k] + dtu * bcv[0];
      h1[k] = __expf(A1[k] * dt) * h1[k] + dtu * bcv[1];
      const float y = h0[k] * bcv[2] + h1[k] * bcv[3];
      const float z = bf2f(zv[k]);
      const float sz = z / (1.f + __expf(-z));
      o[k] = f2bf((y + dsk[k] * uu) * sz);
    }
    *(u16x4*)(yb + row * DI + d0) = o;    // in-place over dtb: ok
  }
}

// ---------------------------------------------------------------------------
extern "C" void kernel_launch(void* const* d_in, const int* in_sizes, int n_in,
                              void* d_out, int out_size, void* d_ws, size_t ws_size,
                              hipStream_t stream)
{
  const void* x       = d_in[0];
  const void* w_in    = d_in[1];
  const void* conv_w  = d_in[2];
  const void* conv_b  = d_in[3];
  const void* w_xproj = d_in[4];
  const void* w_dt    = d_in[5];
  const void* b_dt    = d_in[6];
  const void* a_log   = d_in[7];
  const void* d_skip  = d_in[8];
  const void* w_out   = d_in[9];
  const void* ln1_g   = d_in[10];
  const void* ln1_b   = d_in[11];
  const void* ln2_g   = d_in[12];
  const void* ln2_b   = d_in[13];
  const void* ffn_w1  = d_in[14];
  const void* ffn_b1  = d_in[15];
  const void* ffn_w2  = d_in[16];
  const void* ffn_b2  = d_in[17];
  char* ws = (char*)d_ws;

  // ---- workspace layout (high-water ~127 MB) ----
  const size_t o_flag  = 0;
  const size_t o_small = 256;
  const size_t o_cwout = o_small + 65536;
  const size_t o_cff1  = o_cwout + (size_t)DM * DI * 2;
  const size_t o_cff2  = o_cff1  + (size_t)DM * DM * 2;
  const size_t o_cxp   = o_cff2  + (size_t)DM * DM * 2;
  const size_t o_cwdt  = o_cxp   + (size_t)NXP * DI * 2;
  const size_t o_xn    = 9437184;                         // 16 MiB region
  const size_t o_xp    = o_xn + (size_t)NTOK * DM * 2;    // 32 MiB
  const size_t o_z     = o_xp + (size_t)NTOK * DI * 2;    // 32 MiB
  const size_t o_u     = o_z  + (size_t)NTOK * DI * 2;    // 32 MiB
  const size_t o_bc    = o_u  + (size_t)NTOK * DI * 2;    // 128 KiB
  // scan state overlays the xn region (dead during the scan):
  const size_t SCN = (size_t)NCHK * NCH * 4;              // 2 MiB each
  const size_t o_S   = o_xn + 0 * SCN;
  const size_t o_hf0 = o_xn + 1 * SCN;
  const size_t o_hf1 = o_xn + 2 * SCN;
  const size_t o_hi0 = o_xn + 3 * SCN;
  const size_t o_hi1 = o_xn + 4 * SCN;                    // ends +10 MiB < 16 MiB

  int*   flagp   = (int*)(ws + o_flag);
  u16*   csmall  = (u16*)(ws + o_small);
  u16*   c_cwT   = csmall +     0;       // transposed conv weights [4][DI]
  u16*   c_convb = csmall +  8192;
  u16*   c_bdt   = csmall + 10240;
  u16*   c_alog  = csmall + 12288;
  u16*   c_dskip = csmall + 16384;
  u16*   c_ln1g  = csmall + 18432;
  u16*   c_ln1b  = csmall + 19456;
  u16*   c_ln2g  = csmall + 20480;
  u16*   c_ln2b  = csmall + 21504;
  u16*   c_fb1   = csmall + 22528;
  u16*   c_fb2   = csmall + 23552;
  u16*   c_wout  = (u16*)(ws + o_cwout);
  u16*   c_ff1   = (u16*)(ws + o_cff1);
  u16*   c_ff2   = (u16*)(ws + o_cff2);
  u16*   c_xproj = (u16*)(ws + o_cxp);
  u16*   c_wdt   = (u16*)(ws + o_cwdt);
  u16*   c_win   = (u16*)(ws + o_u);     // overlays u (dead until conv)
  u16*   xn      = (u16*)(ws + o_xn);
  u16*   xp      = (u16*)(ws + o_xp);
  u16*   zb      = (u16*)(ws + o_z);
  u16*   u       = (u16*)(ws + o_u);
  float* part    = (float*)(ws + o_xp);  // overlays xp (dead after conv)
  u16*   dtraw   = (u16*)(ws + o_xn);    // overlays xn (dead after in_proj)
  u16*   dtb     = xp;                   // overlays part (dead after reduce)
  u16*   yb      = xp;
  float* bc      = (float*)(ws + o_bc);
  float* S       = (float*)(ws + o_S);   // scan arrays overlay xn region;
  float* hf0     = (float*)(ws + o_hf0); // dtraw (first 1 MB) is consumed by
  float* hf1     = (float*)(ws + o_hf1); // the dt-GEMM before pass1 writes S
  float* hi0     = (float*)(ws + o_hi0);
  float* hi1     = (float*)(ws + o_hi1);
  float* h       = (float*)(ws + o_z);   // overlays z (dead after pass3)
  u16*   hn      = (u16*)(ws + o_xn);    // overlays scan arrays (dead)
  u16*   f1      = (u16*)(ws + o_u);     // overlays u (dead)

  const dim3 blk(256);

  // 0) detect dtype; weight copies are no-ops when inputs are already bf16
  detect_kernel<<<1, blk, 0, stream>>>((const u16*)x, flagp);
  convert_big<<<4228, blk, 0, stream>>>(
      (const float*)w_in, (const float*)w_xproj, (const float*)w_dt,
      (const float*)w_out, (const float*)ffn_w1, (const float*)ffn_w2,
      c_win, c_xproj, c_wdt, c_wout, c_ff1, c_ff2, flagp);
  convert_small_kernel<<<96, blk, 0, stream>>>(conv_w, conv_b, b_dt, a_log, d_skip,
                                               ln1_g, ln1_b, ln2_g, ln2_b, ffn_b1, ffn_b2,
                                               csmall, flagp);

  // 1) LN1(x) -> xn
  ln_kernel<true><<<NTOK / 2, blk, 0, stream>>>(x, c_ln1g, c_ln1b, xn, flagp);
  // 2) fused in_proj: [xp | z] = xn @ w_in^T   (N=4096 -> LNBX=5, 2048 blocks)
  gemm_kernel<6, 5><<<2048, blk, 0, stream>>>(xn, c_win, (const u16*)w_in,
                                              NTOK, 2 * DI, DM,
                                              nullptr, nullptr, nullptr, flagp, xp, zb);
  // 3) u = silu(conv(xp) + conv_b)
  conv_silu_kernel<<<NTOK, blk, 0, stream>>>(xp, c_cwT, c_convb, u);
  // 4) x_proj split-K (partials) + reduce -> dtraw (bf16), bc (f32)
  xproj_splitk<<<dim3(8, 64), blk, 0, stream>>>(u, c_xproj, (const u16*)w_xproj,
                                                flagp, part);
  xreduce_kernel<<<(NTOK * NXP + 255) / 256, blk, 0, stream>>>(part, dtraw, bc);
  // 5) dt = softplus(dtraw @ w_dt^T + b_dt)   (N=2048 -> LNBX=4)
  gemm_kernel<2, 4><<<1024, blk, 0, stream>>>(dtraw, c_wdt, (const u16*)w_dt,
                                              NTOK, DI, DTR,
                                              c_bdt, nullptr, nullptr, flagp, dtb, nullptr);
  // 6) chunked scan -> yb = (y + d_skip*u) * silu(z)
  scan_pass1<<<NCHK * NCH / 4 / 256, blk, 0, stream>>>(dtb, u, bc, c_alog, S, hf0, hf1);
  scan_pass2<<<NCH / 256, blk, 0, stream>>>(S, hf0, hf1, c_alog, hi0, hi1);
  scan_pass3<<<NCHK * NCH / 4 / 256, blk, 0, stream>>>(dtb, u, bc, zb, c_alog, c_dskip,
                                                       hi0, hi1, yb);
  // 7) h = x + yb @ w_out^T   (N=1024 -> LNBX=3)
  gemm_kernel<3, 3><<<512, blk, 0, stream>>>(yb, c_wout, (const u16*)w_out,
                                             NTOK, DM, DI,
                                             nullptr, (const u16*)x, (const float*)x,
                                             flagp, h, nullptr);
  // 8) LN2(h) -> hn
  ln_kernel<false><<<NTOK / 2, blk, 0, stream>>>(h, c_ln2g, c_ln2b, hn, flagp);
  // 9) f1 = relu(hn @ ffn_w1^T + b1)
  gemm_kernel<4, 3><<<512, blk, 0, stream>>>(hn, c_ff1, (const u16*)ffn_w1,
                                             NTOK, DM, DM,
                                             c_fb1, nullptr, nullptr, flagp, f1, nullptr);
  // 10) out = h + f1 @ ffn_w2^T + b2
  gemm_kernel<5, 3><<<512, blk, 0, stream>>>(f1, c_ff2, (const u16*)ffn_w2,
                                             NTOK, DM, DM,
                                             c_fb2, nullptr, h, flagp, d_out, nullptr);
}